// Round 1
// baseline (945.228 us; speedup 1.0000x reference)
//
#include <hip/hip_runtime.h>
#include <math.h>

#define N_PTS   8192
#define F_IN    64
#define D_E     4
#define H_DIM   128
#define OUT_DIM 128
#define K_NBR   64
#define E_G     262144
#define MSG_DIM 72           // F_IN + 4 + D_E
#define HASH_BITS 20
#define HASH_SIZE (1u << HASH_BITS)
#define HASH_MASK (HASH_SIZE - 1u)
#define HASH_EMPTY 0xFFFFFFFFu
#define CAND_CAP 512

__device__ __forceinline__ unsigned hash_fn(unsigned key) {
    return (key * 2654435761u) >> (32 - HASH_BITS);
}

// ---------------------------------------------------------------- build hash
__global__ __launch_bounds__(256) void build_hash_kernel(
    const int* __restrict__ ei, unsigned* __restrict__ hkeys,
    unsigned* __restrict__ hvals) {
    int e = blockIdx.x * 256 + threadIdx.x;
    if (e >= E_G) return;
    unsigned key = (unsigned)(ei[e] * N_PTS + ei[E_G + e]);
    unsigned h = hash_fn(key);
    for (;;) {
        unsigned old = atomicCAS(&hkeys[h], HASH_EMPTY, key);
        if (old == HASH_EMPTY || old == key) {
            atomicMin(&hvals[h], (unsigned)e);   // stable-argsort: min edge id wins
            break;
        }
        h = (h + 1u) & HASH_MASK;
    }
}

// ----------------------------------------------------------- neighbor search
__global__ __launch_bounds__(256) void nbr_kernel(
    const float* __restrict__ pos, const int* __restrict__ batch,
    int* __restrict__ nbr, int* __restrict__ ncnt) {
    __shared__ int s_cnt;
    __shared__ float s_d2[CAND_CAP];
    __shared__ int s_j[CAND_CAP];
    int i = blockIdx.x;
    int t = threadIdx.x;
    if (t == 0) s_cnt = 0;
    __syncthreads();
    int b = batch[i];
    // batch is sorted: binary search the [lo, hi) range of batch value b
    int lo; { int a = 0, c = N_PTS; while (a < c) { int m = (a + c) >> 1; if (batch[m] < b) a = m + 1; else c = m; } lo = a; }
    int hi; { int a = lo, c = N_PTS; while (a < c) { int m = (a + c) >> 1; if (batch[m] <= b) a = m + 1; else c = m; } hi = a; }
    float xi = pos[i * 3 + 0], yi = pos[i * 3 + 1], zi = pos[i * 3 + 2];
    float p2i = xi * xi + yi * yi + zi * zi;
    for (int j = lo + t; j < hi; j += 256) {
        float xj = pos[j * 3 + 0], yj = pos[j * 3 + 1], zj = pos[j * 3 + 2];
        float p2j = xj * xj + yj * yj + zj * zj;
        float dt  = xi * xj + yi * yj + zi * zj;
        float d2  = p2i + p2j - 2.0f * dt;   // matches ref formula; self -> exactly 0
        if (d2 <= 4.0f) {
            int p = atomicAdd(&s_cnt, 1);
            if (p < CAND_CAP) { s_d2[p] = d2; s_j[p] = j; }
        }
    }
    __syncthreads();
    int m = s_cnt < CAND_CAP ? s_cnt : CAND_CAP;
    if (m <= K_NBR) {
        for (int s = t; s < m; s += 256) nbr[i * K_NBR + s] = s_j[s];
        if (t == 0) ncnt[i] = m;
    } else {
        // exact top-K by (dist2 asc, index asc) — matches jax.lax.top_k tie-break
        for (int idx = t; idx < m; idx += 256) {
            float d2 = s_d2[idx]; int jj = s_j[idx];
            int rank = 0;
            for (int u = 0; u < m; ++u) {
                float du = s_d2[u]; int ju = s_j[u];
                rank += (du < d2) || (du == d2 && ju < jj);
            }
            if (rank < K_NBR) nbr[i * K_NBR + rank] = jj;
        }
        if (t == 0) ncnt[i] = K_NBR;
    }
}

// --------------------------------------------------------------- angle (ppf)
__device__ __forceinline__ float angle3(float ax, float ay, float az,
                                        float bx, float by, float bz) {
    float cx = ay * bz - az * by;
    float cy = az * bx - ax * bz;
    float cz = ax * by - ay * bx;
    float cs = cx * cx + cy * cy + cz * cz;
    float cn = cs > 0.0f ? sqrtf(cs) : 0.0f;
    float d  = ax * bx + ay * by + az * bz;
    if (cn == 0.0f && d == 0.0f) d = 1.0f;   // atan2(0,1)=0 convention
    return atan2f(cn, d);
}

// ------------------------------------------------------- fused msg+MLP+max
__global__ __launch_bounds__(256) void mlp_kernel(
    const float* __restrict__ x, const float* __restrict__ pos,
    const float* __restrict__ normal, const float* __restrict__ edge_attr,
    const unsigned* __restrict__ hkeys, const unsigned* __restrict__ hvals,
    const int* __restrict__ nbr, const int* __restrict__ ncnt,
    const float* __restrict__ W1, const float* __restrict__ b1,
    const float* __restrict__ W2, const float* __restrict__ b2,
    const float* __restrict__ Wg, const float* __restrict__ bg,
    float* __restrict__ out) {
    __shared__ __align__(16) float s_msg[K_NBR][MSG_DIM];
    __shared__ __align__(16) float s_h1[K_NBR][H_DIM];
    __shared__ float s_agg[256];
    __shared__ int s_nbr[K_NBR];

    int i = blockIdx.x;
    int t = threadIdx.x;
    int cnt = ncnt[i];
    if (t < K_NBR && t < cnt) s_nbr[t] = nbr[i * K_NBR + t];
    __syncthreads();

    float pxi = pos[i * 3 + 0], pyi = pos[i * 3 + 1], pzi = pos[i * 3 + 2];
    float nxi = normal[i * 3 + 0], nyi = normal[i * 3 + 1], nzi = normal[i * 3 + 2];

    // ---- build msg[k][0:72] = [x_j(64), ppf(4), eattr(4)]
    int k = t >> 2, q = t & 3;
    if (k < cnt) {
        int j = s_nbr[k];
        const float4* xr = (const float4*)(x + (size_t)j * F_IN);
        float4* mr = (float4*)(&s_msg[k][0]);
        #pragma unroll
        for (int u = 0; u < 4; ++u) mr[q * 4 + u] = xr[q * 4 + u];
        if (q == 0) {
            float pxj = pos[j * 3 + 0], pyj = pos[j * 3 + 1], pzj = pos[j * 3 + 2];
            float vx = pxj - pxi, vy = pyj - pyi, vz = pzj - pzi;
            float nxj = normal[j * 3 + 0], nyj = normal[j * 3 + 1], nzj = normal[j * 3 + 2];
            float sq = vx * vx + vy * vy + vz * vz;
            s_msg[k][64] = sq > 0.0f ? sqrtf(sq) : 0.0f;
            s_msg[k][65] = angle3(nxi, nyi, nzi, vx, vy, vz);
            s_msg[k][66] = angle3(nxj, nyj, nzj, vx, vy, vz);
            s_msg[k][67] = angle3(nxi, nyi, nzi, nxj, nyj, nzj);
        } else if (q == 1) {
            unsigned key = (unsigned)(j * N_PTS + i);
            unsigned h = hash_fn(key);
            unsigned eidx = E_G;   // sentinel row
            for (;;) {
                unsigned k2 = hkeys[h];
                if (k2 == key) { eidx = hvals[h]; break; }
                if (k2 == HASH_EMPTY) break;
                h = (h + 1u) & HASH_MASK;
            }
            const float* er = edge_attr + (size_t)eidx * D_E;
            s_msg[k][68] = er[0]; s_msg[k][69] = er[1];
            s_msg[k][70] = er[2]; s_msg[k][71] = er[3];
        }
    }
    __syncthreads();

    int c = t & 127, kk = t >> 7;

    // ---- layer 1: h1 = relu(msg @ W1 + b1)   (W1 column held in regs)
    {
        float w1c[MSG_DIM];
        #pragma unroll
        for (int f = 0; f < MSG_DIM; ++f) w1c[f] = W1[f * H_DIM + c];
        float bb1 = b1[c];
        for (int k2 = kk; k2 < cnt; k2 += 2) {
            float acc = bb1;
            #pragma unroll
            for (int f = 0; f < MSG_DIM; ++f) acc += s_msg[k2][f] * w1c[f];
            s_h1[k2][c] = fmaxf(acc, 0.0f);
        }
    }
    __syncthreads();

    // ---- layer 2 + max-aggregate
    {
        float w2c[H_DIM];
        #pragma unroll
        for (int h = 0; h < H_DIM; ++h) w2c[h] = W2[h * H_DIM + c];
        float bb2 = b2[c];
        float mx = -INFINITY;
        for (int k2 = kk; k2 < cnt; k2 += 2) {
            float acc = bb2;
            #pragma unroll
            for (int h = 0; h < H_DIM; ++h) acc += s_h1[k2][h] * w2c[h];
            mx = fmaxf(mx, fmaxf(acc, 0.0f));
        }
        s_agg[t] = mx;
    }
    __syncthreads();
    if (t < 128) s_agg[t] = fmaxf(s_agg[t], s_agg[t + 128]);
    __syncthreads();

    // ---- global_nn: out = agg @ Wg + bg
    if (t < 128) {
        float acc = bg[t];
        #pragma unroll 16
        for (int h = 0; h < H_DIM; ++h) acc += s_agg[h] * Wg[h * OUT_DIM + t];
        out[(size_t)i * OUT_DIM + t] = acc;
    }
}

// --------------------------------------------------------- tail: pos + batch
__global__ __launch_bounds__(256) void tail_kernel(
    const float* __restrict__ pos, const int* __restrict__ batch,
    float* __restrict__ out) {
    int idx = blockIdx.x * 256 + threadIdx.x;
    if (idx < N_PTS * 3) out[N_PTS * OUT_DIM + idx] = pos[idx];
    if (idx < N_PTS)     out[N_PTS * OUT_DIM + N_PTS * 3 + idx] = (float)batch[idx];
}

// ---------------------------------------------------------------------------
extern "C" void kernel_launch(void* const* d_in, const int* in_sizes, int n_in,
                              void* d_out, int out_size, void* d_ws, size_t ws_size,
                              hipStream_t stream) {
    const float* x         = (const float*)d_in[0];
    const float* pos       = (const float*)d_in[1];
    const float* normal    = (const float*)d_in[2];
    const int*   batch     = (const int*)d_in[3];
    const float* edge_attr = (const float*)d_in[4];
    const int*   edge_index= (const int*)d_in[5];
    const float* W1        = (const float*)d_in[6];
    const float* b1        = (const float*)d_in[7];
    const float* W2        = (const float*)d_in[8];
    const float* b2        = (const float*)d_in[9];
    const float* Wg        = (const float*)d_in[10];
    const float* bg        = (const float*)d_in[11];
    float* out = (float*)d_out;

    char* w = (char*)d_ws;
    unsigned* hkeys = (unsigned*)w;                              // 4 MB
    unsigned* hvals = (unsigned*)(w + (size_t)HASH_SIZE * 4);    // 4 MB
    int* nbr  = (int*)(w + (size_t)HASH_SIZE * 8);               // 2 MB
    int* ncnt = (int*)(w + (size_t)HASH_SIZE * 8 + (size_t)N_PTS * K_NBR * 4);

    // hash table: keys=EMPTY, vals=UINT_MAX (memset 0xFF covers both)
    hipMemsetAsync(hkeys, 0xFF, (size_t)HASH_SIZE * 8, stream);

    build_hash_kernel<<<E_G / 256, 256, 0, stream>>>(edge_index, hkeys, hvals);
    nbr_kernel<<<N_PTS, 256, 0, stream>>>(pos, batch, nbr, ncnt);
    mlp_kernel<<<N_PTS, 256, 0, stream>>>(x, pos, normal, edge_attr,
                                          hkeys, hvals, nbr, ncnt,
                                          W1, b1, W2, b2, Wg, bg, out);
    tail_kernel<<<(N_PTS * 3 + 255) / 256, 256, 0, stream>>>(pos, batch, out);
}

// Round 2
// 178.121 us; speedup vs baseline: 5.3067x; 5.3067x over previous
//
#include <hip/hip_runtime.h>
#include <math.h>

#define N_PTS   8192
#define F_IN    64
#define D_E     4
#define H_DIM   128
#define OUT_DIM 128
#define K_NBR   64
#define E_G     262144
#define HASH_BITS 19
#define HASH_SIZE (1u << HASH_BITS)
#define HASH_MASK (HASH_SIZE - 1u)
#define HASH_EMPTY 0xFFFFFFFFu
#define CAND_CAP 512
#define RS 136   // LDS row stride in ushorts (272 B = 68 dwords -> 2-way bank aliasing, free)

typedef __attribute__((ext_vector_type(8))) short bf16x8;
typedef __attribute__((ext_vector_type(4))) float f32x4;
typedef __attribute__((ext_vector_type(4))) unsigned short us4;
typedef __attribute__((ext_vector_type(2))) unsigned short us2;
typedef __attribute__((ext_vector_type(8))) unsigned short us8;

__device__ __forceinline__ unsigned hash_fn(unsigned key) {
    return (key * 2654435761u) >> (32 - HASH_BITS);
}
__device__ __forceinline__ unsigned short f2bf(float f) {   // RNE f32->bf16
    union { float f; unsigned u; } v; v.f = f;
    unsigned r = v.u + 0x7FFFu + ((v.u >> 16) & 1u);
    return (unsigned short)(r >> 16);
}

// ---------------------------------------------------------------- build hash
__global__ __launch_bounds__(256) void build_hash_kernel(
    const int* __restrict__ ei, unsigned* __restrict__ hkeys,
    unsigned* __restrict__ hvals) {
    int e = blockIdx.x * 256 + threadIdx.x;
    if (e >= E_G) return;
    unsigned key = (unsigned)(ei[e] * N_PTS + ei[E_G + e]);
    unsigned h = hash_fn(key);
    for (;;) {
        unsigned old = atomicCAS(&hkeys[h], HASH_EMPTY, key);
        if (old == HASH_EMPTY || old == key) {
            atomicMin(&hvals[h], (unsigned)e);   // stable-argsort: min edge id wins
            break;
        }
        h = (h + 1u) & HASH_MASK;
    }
}

// ----------------------------------------------------------- neighbor search
__global__ __launch_bounds__(256) void nbr_kernel(
    const float* __restrict__ pos, const int* __restrict__ batch,
    int* __restrict__ nbr, int* __restrict__ ncnt) {
    __shared__ int s_cnt;
    __shared__ float s_d2[CAND_CAP];
    __shared__ int s_j[CAND_CAP];
    int i = blockIdx.x;
    int t = threadIdx.x;
    if (t == 0) s_cnt = 0;
    __syncthreads();
    int b = batch[i];
    int lo; { int a = 0, c = N_PTS; while (a < c) { int m = (a + c) >> 1; if (batch[m] < b) a = m + 1; else c = m; } lo = a; }
    int hi; { int a = lo, c = N_PTS; while (a < c) { int m = (a + c) >> 1; if (batch[m] <= b) a = m + 1; else c = m; } hi = a; }
    float xi = pos[i * 3 + 0], yi = pos[i * 3 + 1], zi = pos[i * 3 + 2];
    float p2i = xi * xi + yi * yi + zi * zi;
    for (int j = lo + t; j < hi; j += 256) {
        float xj = pos[j * 3 + 0], yj = pos[j * 3 + 1], zj = pos[j * 3 + 2];
        float p2j = xj * xj + yj * yj + zj * zj;
        float dt  = xi * xj + yi * yj + zi * zj;
        float d2  = p2i + p2j - 2.0f * dt;
        if (d2 <= 4.0f) {
            int pp = atomicAdd(&s_cnt, 1);
            if (pp < CAND_CAP) { s_d2[pp] = d2; s_j[pp] = j; }
        }
    }
    __syncthreads();
    int m = s_cnt < CAND_CAP ? s_cnt : CAND_CAP;
    if (m <= K_NBR) {
        for (int s = t; s < m; s += 256) nbr[i * K_NBR + s] = s_j[s];
        if (t == 0) ncnt[i] = m;
    } else {
        for (int idx = t; idx < m; idx += 256) {
            float d2 = s_d2[idx]; int jj = s_j[idx];
            int rank = 0;
            for (int u = 0; u < m; ++u) {
                float du = s_d2[u]; int ju = s_j[u];
                rank += (du < d2) || (du == d2 && ju < jj);
            }
            if (rank < K_NBR) nbr[i * K_NBR + rank] = jj;
        }
        if (t == 0) ncnt[i] = K_NBR;
    }
}

// --------------------------------------------------------------- angle (ppf)
__device__ __forceinline__ float angle3(float ax, float ay, float az,
                                        float bx, float by, float bz) {
    float cx = ay * bz - az * by;
    float cy = az * bx - ax * bz;
    float cz = ax * by - ay * bx;
    float cs = cx * cx + cy * cy + cz * cz;
    float cn = cs > 0.0f ? sqrtf(cs) : 0.0f;
    float d  = ax * bx + ay * by + az * bz;
    if (cn == 0.0f && d == 0.0f) d = 1.0f;
    return atan2f(cn, d);
}

// -------------------------------------------- prep: W1/W2 -> bf16 fragments
// w1f: A-fragments of W1^T (M=c1,K=f).  A-layout: row=l&15, k=(l>>4)*8+i.
//      f==72 row carries b1 (bias-as-feature); f in [73,96) zero.
// w2f: B-fragments of W2 (K=h,N=c2).    B-layout: col=l&15, k=(l>>4)*8+i.
__global__ __launch_bounds__(256) void prep_kernel(
    const float* __restrict__ W1, const float* __restrict__ b1,
    const float* __restrict__ W2,
    unsigned short* __restrict__ w1f, unsigned short* __restrict__ w2f) {
    int t = blockIdx.x * 256 + threadIdx.x;
    if (t < 12288) {   // 3 kt * 8 mt * 64 lane * 8 i
        int i = t & 7, lane = (t >> 3) & 63, mt = (t >> 9) & 7, kt = t >> 12;
        int c1 = mt * 16 + (lane & 15);
        int f  = kt * 32 + (lane >> 4) * 8 + i;
        float v = 0.0f;
        if (f < 72) v = W1[f * H_DIM + c1];
        else if (f == 72) v = b1[c1];
        w1f[t] = f2bf(v);
    }
    if (t < 16384) {   // 4 kt * 8 nt * 64 lane * 8 i
        int i = t & 7, lane = (t >> 3) & 63, nt = (t >> 9) & 7, kt = t >> 12;
        int c2 = nt * 16 + (lane & 15);
        int h  = kt * 32 + (lane >> 4) * 8 + i;
        w2f[t] = f2bf(W2[h * H_DIM + c2]);
    }
}

// ------------------------------------ fused msg-build + MFMA MLP + max-agg
// Block = 128 threads = 2 waves; each wave owns one point (64 slots).
// LDS buf rows [wb, wb+64): first msg [slot][f(0..95)], then in-place h1 [slot][c1(0..127)].
__global__ __launch_bounds__(128) void mlp_kernel(
    const float* __restrict__ x, const float* __restrict__ pos,
    const float* __restrict__ normal, const float* __restrict__ edge_attr,
    const unsigned* __restrict__ hkeys, const unsigned* __restrict__ hvals,
    const int* __restrict__ nbr, const int* __restrict__ ncnt,
    const unsigned short* __restrict__ w1f, const unsigned short* __restrict__ w2f,
    const float* __restrict__ b2, float* __restrict__ agg) {
    __shared__ unsigned short buf[128 * RS];   // 34,816 B
    __shared__ int s_nbr[128];
    int tid = threadIdx.x;
    int w = tid >> 6, l = tid & 63;
    int p  = blockIdx.x * 2 + w;
    int wb = w * 64;
    int lo16 = l & 15, hi4 = l >> 4;
    int cnt = ncnt[p];

    int jme = (l < cnt) ? nbr[p * K_NBR + l] : -1;
    s_nbr[wb + l] = jme;

    // zero msg cols [0,96) of own row; bias-feature col 72 = 1.0
    {
        us8* r = (us8*)(buf + (wb + l) * RS);
        us8 z = (us8)0;
        #pragma unroll
        for (int u = 0; u < 12; ++u) r[u] = z;
        buf[(wb + l) * RS + 72] = 0x3F80;   // bf16(1.0)
    }

    // gather x[j] -> msg cols [0,64): 4 passes, 4 lanes per slot
    #pragma unroll
    for (int q = 0; q < 4; ++q) {
        int s = q * 16 + (l >> 2), part = l & 3;
        int j = s_nbr[wb + s];
        if (j >= 0) {
            const float4* xr = (const float4*)(x + (size_t)j * F_IN);
            unsigned short* dst = buf + (wb + s) * RS + part * 16;
            #pragma unroll
            for (int u = 0; u < 4; ++u) {
                float4 v = xr[part * 4 + u];
                us4 o; o[0] = f2bf(v.x); o[1] = f2bf(v.y); o[2] = f2bf(v.z); o[3] = f2bf(v.w);
                *(us4*)(dst + u * 4) = o;
            }
        }
    }

    // ppf (cols 64..67) + edge_attr (cols 68..71); lane == slot
    if (jme >= 0) {
        int j = jme;
        float pxi = pos[p*3], pyi = pos[p*3+1], pzi = pos[p*3+2];
        float nxi = normal[p*3], nyi = normal[p*3+1], nzi = normal[p*3+2];
        float pxj = pos[j*3], pyj = pos[j*3+1], pzj = pos[j*3+2];
        float nxj = normal[j*3], nyj = normal[j*3+1], nzj = normal[j*3+2];
        float vx = pxj - pxi, vy = pyj - pyi, vz = pzj - pzi;
        float sq = vx*vx + vy*vy + vz*vz;
        float dd = sq > 0.0f ? sqrtf(sq) : 0.0f;
        float a1 = angle3(nxi,nyi,nzi, vx,vy,vz);
        float a2 = angle3(nxj,nyj,nzj, vx,vy,vz);
        float a3 = angle3(nxi,nyi,nzi, nxj,nyj,nzj);
        unsigned short* dst = buf + (wb + l) * RS;
        us2 o01; o01[0] = f2bf(dd); o01[1] = f2bf(a1); *(us2*)(dst + 64) = o01;
        us2 o23; o23[0] = f2bf(a2); o23[1] = f2bf(a3); *(us2*)(dst + 66) = o23;
        unsigned key = (unsigned)(j * N_PTS + p);
        unsigned hh = hash_fn(key);
        unsigned eidx = E_G;   // sentinel row
        for (;;) {
            unsigned k2 = hkeys[hh];
            if (k2 == key) { eidx = hvals[hh]; break; }
            if (k2 == HASH_EMPTY) break;
            hh = (hh + 1u) & HASH_MASK;
        }
        float4 er = *(const float4*)(edge_attr + (size_t)eidx * D_E);
        us2 o45; o45[0] = f2bf(er.x); o45[1] = f2bf(er.y); *(us2*)(dst + 68) = o45;
        us2 o67; o67[0] = f2bf(er.z); o67[1] = f2bf(er.w); *(us2*)(dst + 70) = o67;
    }

    // ---- layer 1 (transposed): D1[c1][slot] = W1^T x msg^T.  96 MFMAs.
    f32x4 acc1[8][4];
    #pragma unroll
    for (int mt = 0; mt < 8; ++mt)
        #pragma unroll
        for (int ns = 0; ns < 4; ++ns) acc1[mt][ns] = (f32x4)0.0f;
    #pragma unroll
    for (int kt = 0; kt < 3; ++kt) {
        bf16x8 bfr[4];
        #pragma unroll
        for (int ns = 0; ns < 4; ++ns) {
            int row = wb + ns * 16 + lo16;
            bfr[ns] = *(const bf16x8*)(buf + row * RS + kt * 32 + hi4 * 8);
        }
        #pragma unroll
        for (int mt = 0; mt < 8; ++mt) {
            bf16x8 afr = *(const bf16x8*)(w1f + (((kt * 8 + mt) * 64) + l) * 8);
            #pragma unroll
            for (int ns = 0; ns < 4; ++ns)
                acc1[mt][ns] = __builtin_amdgcn_mfma_f32_16x16x32_bf16(afr, bfr[ns], acc1[mt][ns], 0, 0, 0);
        }
    }
    // relu + store h1^T in place: buf[slot][c1] (packed 4 x bf16 = 8 B writes)
    #pragma unroll
    for (int mt = 0; mt < 8; ++mt)
        #pragma unroll
        for (int ns = 0; ns < 4; ++ns) {
            int slot = ns * 16 + lo16;
            int c1   = mt * 16 + hi4 * 4;
            us4 o;
            o[0] = f2bf(fmaxf(acc1[mt][ns][0], 0.0f));
            o[1] = f2bf(fmaxf(acc1[mt][ns][1], 0.0f));
            o[2] = f2bf(fmaxf(acc1[mt][ns][2], 0.0f));
            o[3] = f2bf(fmaxf(acc1[mt][ns][3], 0.0f));
            *(us4*)(buf + (wb + slot) * RS + c1) = o;
        }

    // ---- layer 2: D2[slot][c2] = h1 x W2 (+b2 via acc init).  128 MFMAs.
    f32x4 acc2[4][8];
    #pragma unroll
    for (int nt = 0; nt < 8; ++nt) {
        float bb = b2[nt * 16 + lo16];
        f32x4 bv = {bb, bb, bb, bb};
        #pragma unroll
        for (int ms = 0; ms < 4; ++ms) acc2[ms][nt] = bv;
    }
    #pragma unroll
    for (int kt = 0; kt < 4; ++kt) {
        bf16x8 afr[4];
        #pragma unroll
        for (int ms = 0; ms < 4; ++ms) {
            int slot = ms * 16 + lo16;
            afr[ms] = *(const bf16x8*)(buf + (wb + slot) * RS + kt * 32 + hi4 * 8);
        }
        #pragma unroll
        for (int nt = 0; nt < 8; ++nt) {
            bf16x8 bfr = *(const bf16x8*)(w2f + (((kt * 8 + nt) * 64) + l) * 8);
            #pragma unroll
            for (int ms = 0; ms < 4; ++ms)
                acc2[ms][nt] = __builtin_amdgcn_mfma_f32_16x16x32_bf16(afr[ms], bfr, acc2[ms][nt], 0, 0, 0);
        }
    }

    // ---- relu + masked max over slots + write agg
    #pragma unroll
    for (int nt = 0; nt < 8; ++nt) {
        float m = -INFINITY;
        #pragma unroll
        for (int ms = 0; ms < 4; ++ms)
            #pragma unroll
            for (int r = 0; r < 4; ++r) {
                int slot = ms * 16 + hi4 * 4 + r;
                float v = fmaxf(acc2[ms][nt][r], 0.0f);
                m = fmaxf(m, slot < cnt ? v : -INFINITY);
            }
        m = fmaxf(m, __shfl_xor(m, 16, 64));
        m = fmaxf(m, __shfl_xor(m, 32, 64));
        if (l < 16) agg[(size_t)p * H_DIM + nt * 16 + l] = m;
    }
}

// ------------------------------------------------- global_nn: out = agg@Wg+bg
__global__ __launch_bounds__(256) void final_kernel(
    const float* __restrict__ agg, const float* __restrict__ Wg,
    const float* __restrict__ bg, float* __restrict__ out) {
    __shared__ float s[256];
    int t = threadIdx.x;
    s[t] = agg[(size_t)blockIdx.x * 256 + t];
    __syncthreads();
    int i = t >> 7, c = t & 127;
    const float* a = s + i * 128;
    float accv = bg[c];
    #pragma unroll 8
    for (int h = 0; h < 128; ++h) accv += a[h] * Wg[h * OUT_DIM + c];
    out[((size_t)blockIdx.x * 2 + i) * OUT_DIM + c] = accv;
}

// --------------------------------------------------------- tail: pos + batch
__global__ __launch_bounds__(256) void tail_kernel(
    const float* __restrict__ pos, const int* __restrict__ batch,
    float* __restrict__ out) {
    int idx = blockIdx.x * 256 + threadIdx.x;
    if (idx < N_PTS * 3) out[N_PTS * OUT_DIM + idx] = pos[idx];
    if (idx < N_PTS)     out[N_PTS * OUT_DIM + N_PTS * 3 + idx] = (float)batch[idx];
}

// ---------------------------------------------------------------------------
extern "C" void kernel_launch(void* const* d_in, const int* in_sizes, int n_in,
                              void* d_out, int out_size, void* d_ws, size_t ws_size,
                              hipStream_t stream) {
    const float* x         = (const float*)d_in[0];
    const float* pos       = (const float*)d_in[1];
    const float* normal    = (const float*)d_in[2];
    const int*   batch     = (const int*)d_in[3];
    const float* edge_attr = (const float*)d_in[4];
    const int*   edge_index= (const int*)d_in[5];
    const float* W1        = (const float*)d_in[6];
    const float* b1        = (const float*)d_in[7];
    const float* W2        = (const float*)d_in[8];
    const float* b2        = (const float*)d_in[9];
    const float* Wg        = (const float*)d_in[10];
    const float* bg        = (const float*)d_in[11];
    float* out = (float*)d_out;

    unsigned char* wsb = (unsigned char*)d_ws;
    unsigned* hkeys = (unsigned*)wsb;                                   // 2 MB
    unsigned* hvals = (unsigned*)(wsb + (size_t)HASH_SIZE * 4);         // 2 MB
    int* nbr  = (int*)(wsb + (size_t)HASH_SIZE * 8);                    // 2 MB
    int* ncnt = (int*)(wsb + (size_t)HASH_SIZE * 8 + (size_t)N_PTS * K_NBR * 4);
    unsigned short* w1f = (unsigned short*)((unsigned char*)ncnt + (size_t)N_PTS * 4);
    unsigned short* w2f = w1f + 12288;
    float* agg = (float*)((unsigned char*)(w2f + 16384));               // 4 MB

    hipMemsetAsync(hkeys, 0xFF, (size_t)HASH_SIZE * 8, stream);

    build_hash_kernel<<<E_G / 256, 256, 0, stream>>>(edge_index, hkeys, hvals);
    prep_kernel<<<64, 256, 0, stream>>>(W1, b1, W2, w1f, w2f);
    nbr_kernel<<<N_PTS, 256, 0, stream>>>(pos, batch, nbr, ncnt);
    mlp_kernel<<<N_PTS / 2, 128, 0, stream>>>(x, pos, normal, edge_attr,
                                              hkeys, hvals, nbr, ncnt,
                                              w1f, w2f, b2, agg);
    final_kernel<<<N_PTS / 2, 256, 0, stream>>>(agg, Wg, bg, out);
    tail_kernel<<<(N_PTS * 3 + 255) / 256, 256, 0, stream>>>(pos, batch, out);
}

// Round 3
// 153.333 us; speedup vs baseline: 6.1645x; 1.1617x over previous
//
#include <hip/hip_runtime.h>
#include <math.h>

#define N_PTS   8192
#define F_IN    64
#define D_E     4
#define H_DIM   128
#define OUT_DIM 128
#define K_NBR   64
#define E_G     262144
#define HASH_BITS 19
#define HASH_SIZE (1u << HASH_BITS)
#define HASH_MASK (HASH_SIZE - 1u)
#define HASH_EMPTY 0xFFFFFFFFu
#define CAND_CAP 512

typedef __attribute__((ext_vector_type(8))) short bf16x8;
typedef __attribute__((ext_vector_type(4))) float f32x4;
typedef unsigned int u32;

__device__ __forceinline__ unsigned hash_fn(unsigned key) {
    return (key * 2654435761u) >> (32 - HASH_BITS);
}
__device__ __forceinline__ unsigned short f2bf(float f) {   // RNE f32->bf16
    union { float f; unsigned u; } v; v.f = f;
    unsigned r = v.u + 0x7FFFu + ((v.u >> 16) & 1u);
    return (unsigned short)(r >> 16);
}
__device__ __forceinline__ u32 pack2bf(float a, float b) {
    return (u32)f2bf(a) | ((u32)f2bf(b) << 16);
}
__device__ __forceinline__ bf16x8 cvt8(float4 a, float4 b) {
    union { bf16x8 v; u32 d[4]; } u;
    u.d[0] = pack2bf(a.x, a.y); u.d[1] = pack2bf(a.z, a.w);
    u.d[2] = pack2bf(b.x, b.y); u.d[3] = pack2bf(b.z, b.w);
    return u.v;
}
__device__ __forceinline__ int bperm(int byteaddr, u32 v) {
    return __builtin_amdgcn_ds_bpermute(byteaddr, (int)v);
}

// fast atan2 for y >= 0 (y = |cross| is always >= 0); err ~1e-5 rad
__device__ __forceinline__ float fast_atan2p(float y, float x) {
    float ax = fabsf(x);
    float mn = fminf(ax, y), mx = fmaxf(ax, y);
    float rc = mx > 0.0f ? __builtin_amdgcn_rcpf(mx) : 0.0f;
    float r = mn * rc;
    float t2 = r * r;
    float p = r * (0.99997726f + t2 * (-0.33262347f + t2 * (0.19354346f +
              t2 * (-0.11643287f + t2 * (0.05265332f + t2 * (-0.01172120f))))));
    float a = (y > ax) ? (1.5707963267948966f - p) : p;
    if (x < 0.0f) a = 3.14159265358979f - a;
    return a;
}
__device__ __forceinline__ float angle3(float axv, float ayv, float azv,
                                        float bxv, float byv, float bzv) {
    float cx = ayv * bzv - azv * byv;
    float cy = azv * bxv - axv * bzv;
    float cz = axv * byv - ayv * bxv;
    float cs = cx * cx + cy * cy + cz * cz;
    float cn = cs > 0.0f ? sqrtf(cs) : 0.0f;
    float d  = axv * bxv + ayv * byv + azv * bzv;
    return fast_atan2p(cn, d);   // cn==0&&d==0 -> 0, matches atan2(0,1)
}

// ---------------------------------------------------------------- build hash
__global__ __launch_bounds__(256) void build_hash_kernel(
    const int* __restrict__ ei, unsigned* __restrict__ hkeys,
    unsigned* __restrict__ hvals) {
    int e = blockIdx.x * 256 + threadIdx.x;
    if (e >= E_G) return;
    unsigned key = (unsigned)(ei[e] * N_PTS + ei[E_G + e]);
    unsigned h = hash_fn(key);
    for (;;) {
        unsigned old = atomicCAS(&hkeys[h], HASH_EMPTY, key);
        if (old == HASH_EMPTY || old == key) {
            atomicMin(&hvals[h], (unsigned)e);   // stable-argsort: min edge id wins
            break;
        }
        h = (h + 1u) & HASH_MASK;
    }
}

// ----------------------------------------------------- batch segment bounds
__global__ void bounds_kernel(const int* __restrict__ batch, int* __restrict__ bounds) {
    int t = threadIdx.x;
    if (t <= 8) {
        int a = 0, c = N_PTS;
        while (a < c) { int m = (a + c) >> 1; if (batch[m] < t) a = m + 1; else c = m; }
        bounds[t] = a;
    }
}

// ----------------------------------------------------------- neighbor search
// wave per point; ballot-compacted candidate collection
__global__ __launch_bounds__(256) void nbr_kernel(
    const float* __restrict__ pos, const int* __restrict__ batch,
    const int* __restrict__ bounds, int* __restrict__ nbr, int* __restrict__ ncnt) {
    __shared__ float s_d2[4][CAND_CAP];
    __shared__ int   s_j[4][CAND_CAP];
    int tid = threadIdx.x, l = tid & 63, w = tid >> 6;
    int i = blockIdx.x * 4 + w;
    int b = batch[i];
    int lo = bounds[b], hi = bounds[b + 1];
    float xi = pos[i * 3 + 0], yi = pos[i * 3 + 1], zi = pos[i * 3 + 2];
    float p2i = xi * xi + yi * yi + zi * zi;
    int cnt = 0;
    for (int j0 = lo; j0 < hi; j0 += 64) {
        int j = j0 + l;
        bool valid = false; float d2 = 0.0f;
        if (j < hi) {
            float xj = pos[j * 3 + 0], yj = pos[j * 3 + 1], zj = pos[j * 3 + 2];
            float p2j = xj * xj + yj * yj + zj * zj;
            float dt  = xi * xj + yi * yj + zi * zj;
            d2 = p2i + p2j - 2.0f * dt;
            valid = d2 <= 4.0f;
        }
        unsigned long long mask = __ballot(valid);
        int pre = __popcll(mask & ((1ull << l) - 1ull));
        if (valid) {
            int pp = cnt + pre;
            if (pp < CAND_CAP) { s_d2[w][pp] = d2; s_j[w][pp] = j; }
        }
        cnt += __popcll(mask);
    }
    if (cnt > CAND_CAP) cnt = CAND_CAP;
    __syncthreads();
    if (cnt <= K_NBR) {
        if (l < cnt) nbr[i * K_NBR + l] = s_j[w][l];
        if (l == 0) ncnt[i] = cnt;
    } else {
        for (int idx = l; idx < cnt; idx += 64) {   // rare: exact top-K by (d2, j)
            float d2 = s_d2[w][idx]; int jj = s_j[w][idx];
            int rank = 0;
            for (int u = 0; u < cnt; ++u) {
                float du = s_d2[w][u]; int ju = s_j[w][u];
                rank += (du < d2) || (du == d2 && ju < jj);
            }
            if (rank < K_NBR) nbr[i * K_NBR + rank] = jj;
        }
        if (l == 0) ncnt[i] = K_NBR;
    }
}

// -------------------------------------------- prep: W1/W2/Wg -> bf16 frags
__global__ __launch_bounds__(256) void prep_kernel(
    const float* __restrict__ W1, const float* __restrict__ b1,
    const float* __restrict__ W2, const float* __restrict__ Wg,
    unsigned short* __restrict__ w1f, unsigned short* __restrict__ w2f,
    unsigned short* __restrict__ wgf) {
    int t = blockIdx.x * 256 + threadIdx.x;
    if (t < 12288) {   // A-frags of W1^T: 3 kt * 8 mt * 64 lane * 8 i
        int i = t & 7, lane = (t >> 3) & 63, mt = (t >> 9) & 7, kt = t >> 12;
        int c1 = mt * 16 + (lane & 15);
        int f  = kt * 32 + (lane >> 4) * 8 + i;
        float v = 0.0f;
        if (f < 72) v = W1[f * H_DIM + c1];
        else if (f == 72) v = b1[c1];   // bias-as-feature
        w1f[t] = f2bf(v);
    }
    if (t < 16384) {   // B-frags: 4 kt * 8 nt * 64 lane * 8 i
        int i = t & 7, lane = (t >> 3) & 63, nt = (t >> 9) & 7, kt = t >> 12;
        int c = nt * 16 + (lane & 15);
        int h = kt * 32 + (lane >> 4) * 8 + i;
        w2f[t] = f2bf(W2[h * H_DIM + c]);
        wgf[t] = f2bf(Wg[h * OUT_DIM + c]);
    }
}

// ---------------------- fused msg + MFMA MLP + max-agg (zero LDS, wave=point)
__global__ __launch_bounds__(256, 3) void mlp_kernel(
    const float* __restrict__ x, const float* __restrict__ pos,
    const float* __restrict__ normal, const float* __restrict__ edge_attr,
    const unsigned* __restrict__ hkeys, const unsigned* __restrict__ hvals,
    const int* __restrict__ nbr, const int* __restrict__ ncnt,
    const unsigned short* __restrict__ w1f, const unsigned short* __restrict__ w2f,
    const float* __restrict__ b2, float* __restrict__ agg) {
    int tid = threadIdx.x;
    int l = tid & 63, w = tid >> 6;
    int p = blockIdx.x * 4 + w;
    int lo16 = l & 15, hi4 = l >> 4;
    int cnt = ncnt[p];
    int jme = (l < cnt) ? nbr[p * K_NBR + l] : -1;

    // neighbor index of slot ns*16+lo16 (per-lane), then issue all x loads early
    int js[4];
    #pragma unroll
    for (int ns = 0; ns < 4; ++ns)
        js[ns] = bperm((ns * 16 + lo16) << 2, (u32)jme);

    float4 xraw[4][2][2];   // [ns][kt][half]
    #pragma unroll
    for (int ns = 0; ns < 4; ++ns) {
        const float* xb = x + (size_t)max(js[ns], 0) * F_IN;
        #pragma unroll
        for (int kt = 0; kt < 2; ++kt) {
            xraw[ns][kt][0] = *(const float4*)(xb + kt * 32 + hi4 * 8);
            xraw[ns][kt][1] = *(const float4*)(xb + kt * 32 + hi4 * 8 + 4);
        }
    }

    // ---- ppf + edge_attr for own slot (clamped j; invalid slots masked later)
    int jc = max(jme, 0);
    float pxi = pos[p * 3], pyi = pos[p * 3 + 1], pzi = pos[p * 3 + 2];
    float nxi = normal[p * 3], nyi = normal[p * 3 + 1], nzi = normal[p * 3 + 2];
    float pxj = pos[jc * 3], pyj = pos[jc * 3 + 1], pzj = pos[jc * 3 + 2];
    float nxj = normal[jc * 3], nyj = normal[jc * 3 + 1], nzj = normal[jc * 3 + 2];
    float vx = pxj - pxi, vy = pyj - pyi, vz = pzj - pzi;
    float sq = vx * vx + vy * vy + vz * vz;
    float dd = sq > 0.0f ? sqrtf(sq) : 0.0f;
    float a1 = angle3(nxi, nyi, nzi, vx, vy, vz);
    float a2 = angle3(nxj, nyj, nzj, vx, vy, vz);
    float a3 = angle3(nxi, nyi, nzi, nxj, nyj, nzj);
    unsigned key = (unsigned)(jc * N_PTS + p);
    unsigned hh = hash_fn(key);
    unsigned eidx = E_G;   // sentinel row
    for (;;) {
        unsigned k2 = hkeys[hh];
        if (k2 == key) { eidx = hvals[hh]; break; }
        if (k2 == HASH_EMPTY) break;
        hh = (hh + 1u) & HASH_MASK;
    }
    float4 er = *(const float4*)(edge_attr + (size_t)eidx * D_E);
    u32 pk0 = pack2bf(dd, a1),   pk1 = pack2bf(a2, a3);
    u32 pk2 = pack2bf(er.x, er.y), pk3 = pack2bf(er.z, er.w);

    // ---- kt=2 B-frags: f 64..71 (ppf+eattr, hi4==0), f72 bias=1 (hi4==1), else 0
    bf16x8 ktf[4];
    #pragma unroll
    for (int ns = 0; ns < 4; ++ns) {
        int sa = (ns * 16 + lo16) << 2;
        u32 q0 = (u32)bperm(sa, pk0);
        u32 q1 = (u32)bperm(sa, pk1);
        u32 q2 = (u32)bperm(sa, pk2);
        u32 q3 = (u32)bperm(sa, pk3);
        union { bf16x8 v; u32 d[4]; } u;
        u.d[0] = hi4 == 0 ? q0 : (hi4 == 1 ? 0x3F80u : 0u);
        u.d[1] = hi4 == 0 ? q1 : 0u;
        u.d[2] = hi4 == 0 ? q2 : 0u;
        u.d[3] = hi4 == 0 ? q3 : 0u;
        ktf[ns] = u.v;
    }

    // ---- layer 1: D1[c1][slot] = W1^T @ msg^T, redistributed to A-frags haf
    bf16x8 haf[4][4];   // [ms][kt-of-layer2]
    int aA = ((hi4 & 1) * 32 + lo16) << 2;
    int aB = aA + (16 << 2);
    int sel = hi4 >> 1;
    #pragma unroll
    for (int pass = 0; pass < 2; ++pass) {
        bf16x8 xf[2][2];
        #pragma unroll
        for (int nsl = 0; nsl < 2; ++nsl)
            #pragma unroll
            for (int kt = 0; kt < 2; ++kt)
                xf[nsl][kt] = cvt8(xraw[pass * 2 + nsl][kt][0], xraw[pass * 2 + nsl][kt][1]);
        #pragma unroll
        for (int mtp = 0; mtp < 4; ++mtp) {
            u32 ph[2][2][2];   // [sub][nsl][dword]
            #pragma unroll
            for (int sub = 0; sub < 2; ++sub) {
                int mt = mtp * 2 + sub;
                bf16x8 af0 = *(const bf16x8*)(w1f + ((0 * 8 + mt) * 64 + l) * 8);
                bf16x8 af1 = *(const bf16x8*)(w1f + ((1 * 8 + mt) * 64 + l) * 8);
                bf16x8 af2 = *(const bf16x8*)(w1f + ((2 * 8 + mt) * 64 + l) * 8);
                #pragma unroll
                for (int nsl = 0; nsl < 2; ++nsl) {
                    f32x4 acc = (f32x4)0.0f;
                    acc = __builtin_amdgcn_mfma_f32_16x16x32_bf16(af0, xf[nsl][0], acc, 0, 0, 0);
                    acc = __builtin_amdgcn_mfma_f32_16x16x32_bf16(af1, xf[nsl][1], acc, 0, 0, 0);
                    acc = __builtin_amdgcn_mfma_f32_16x16x32_bf16(af2, ktf[pass * 2 + nsl], acc, 0, 0, 0);
                    ph[sub][nsl][0] = pack2bf(fmaxf(acc[0], 0.0f), fmaxf(acc[1], 0.0f));
                    ph[sub][nsl][1] = pack2bf(fmaxf(acc[2], 0.0f), fmaxf(acc[3], 0.0f));
                }
            }
            // requester (lo16,hi4) needs c1 = mtp*32 + hi4*8 + 0..7 of slot ms*16+lo16:
            // sources = lanes aA (r 0..3) and aB (r 4..7) of mt with mt&1 == hi4>>1
            #pragma unroll
            for (int nsl = 0; nsl < 2; ++nsl) {
                u32 A00 = (u32)bperm(aA, ph[0][nsl][0]);
                u32 A10 = (u32)bperm(aA, ph[0][nsl][1]);
                u32 B00 = (u32)bperm(aB, ph[0][nsl][0]);
                u32 B10 = (u32)bperm(aB, ph[0][nsl][1]);
                u32 A01 = (u32)bperm(aA, ph[1][nsl][0]);
                u32 A11 = (u32)bperm(aA, ph[1][nsl][1]);
                u32 B01 = (u32)bperm(aB, ph[1][nsl][0]);
                u32 B11 = (u32)bperm(aB, ph[1][nsl][1]);
                union { bf16x8 v; u32 d[4]; } u;
                u.d[0] = sel ? A01 : A00;
                u.d[1] = sel ? A11 : A10;
                u.d[2] = sel ? B01 : B00;
                u.d[3] = sel ? B11 : B10;
                haf[pass * 2 + nsl][mtp] = u.v;
            }
        }
    }

    // ---- layer 2: D2[slot][c2] = h1 @ W2 (+b2), relu, masked max over slots
    #pragma unroll
    for (int nt = 0; nt < 8; ++nt) {
        float bb = b2[nt * 16 + lo16];
        f32x4 acc[4];
        #pragma unroll
        for (int ms = 0; ms < 4; ++ms) { f32x4 bv = {bb, bb, bb, bb}; acc[ms] = bv; }
        #pragma unroll
        for (int kt = 0; kt < 4; ++kt) {
            bf16x8 bfr = *(const bf16x8*)(w2f + ((kt * 8 + nt) * 64 + l) * 8);
            #pragma unroll
            for (int ms = 0; ms < 4; ++ms)
                acc[ms] = __builtin_amdgcn_mfma_f32_16x16x32_bf16(haf[ms][kt], bfr, acc[ms], 0, 0, 0);
        }
        float m = -INFINITY;
        #pragma unroll
        for (int ms = 0; ms < 4; ++ms)
            #pragma unroll
            for (int r = 0; r < 4; ++r) {
                int slot = ms * 16 + hi4 * 4 + r;
                float v = fmaxf(acc[ms][r], 0.0f);
                m = fmaxf(m, slot < cnt ? v : -INFINITY);
            }
        m = fmaxf(m, __shfl_xor(m, 16, 64));
        m = fmaxf(m, __shfl_xor(m, 32, 64));
        if (l < 16) agg[(size_t)p * H_DIM + nt * 16 + l] = m;
    }
}

// ------------------------------------- global_nn (MFMA): out = agg @ Wg + bg
__global__ __launch_bounds__(256) void final_kernel(
    const float* __restrict__ agg, const unsigned short* __restrict__ wgf,
    const float* __restrict__ bg, float* __restrict__ out) {
    int tid = threadIdx.x, l = tid & 63, w = tid >> 6;
    int pbase = blockIdx.x * 64 + w * 16;
    int lo16 = l & 15, hi4 = l >> 4;
    f32x4 acc[8];
    #pragma unroll
    for (int nt = 0; nt < 8; ++nt) {
        float bb = bg[nt * 16 + lo16];
        f32x4 bv = {bb, bb, bb, bb}; acc[nt] = bv;
    }
    #pragma unroll
    for (int kt = 0; kt < 4; ++kt) {
        const float* ab = agg + (size_t)(pbase + lo16) * H_DIM + kt * 32 + hi4 * 8;
        bf16x8 afr = cvt8(*(const float4*)ab, *(const float4*)(ab + 4));
        #pragma unroll
        for (int nt = 0; nt < 8; ++nt) {
            bf16x8 bfr = *(const bf16x8*)(wgf + ((kt * 8 + nt) * 64 + l) * 8);
            acc[nt] = __builtin_amdgcn_mfma_f32_16x16x32_bf16(afr, bfr, acc[nt], 0, 0, 0);
        }
    }
    #pragma unroll
    for (int nt = 0; nt < 8; ++nt)
        #pragma unroll
        for (int r = 0; r < 4; ++r)
            out[(size_t)(pbase + hi4 * 4 + r) * OUT_DIM + nt * 16 + lo16] = acc[nt][r];
}

// --------------------------------------------------------- tail: pos + batch
__global__ __launch_bounds__(256) void tail_kernel(
    const float* __restrict__ pos, const int* __restrict__ batch,
    float* __restrict__ out) {
    int idx = blockIdx.x * 256 + threadIdx.x;
    if (idx < N_PTS * 3) out[N_PTS * OUT_DIM + idx] = pos[idx];
    if (idx < N_PTS)     out[N_PTS * OUT_DIM + N_PTS * 3 + idx] = (float)batch[idx];
}

// ---------------------------------------------------------------------------
extern "C" void kernel_launch(void* const* d_in, const int* in_sizes, int n_in,
                              void* d_out, int out_size, void* d_ws, size_t ws_size,
                              hipStream_t stream) {
    const float* x         = (const float*)d_in[0];
    const float* pos       = (const float*)d_in[1];
    const float* normal    = (const float*)d_in[2];
    const int*   batch     = (const int*)d_in[3];
    const float* edge_attr = (const float*)d_in[4];
    const int*   edge_index= (const int*)d_in[5];
    const float* W1        = (const float*)d_in[6];
    const float* b1        = (const float*)d_in[7];
    const float* W2        = (const float*)d_in[8];
    const float* b2        = (const float*)d_in[9];
    const float* Wg        = (const float*)d_in[10];
    const float* bg        = (const float*)d_in[11];
    float* out = (float*)d_out;

    unsigned char* wsb = (unsigned char*)d_ws;
    unsigned* hkeys = (unsigned*)wsb;                                   // 2 MB
    unsigned* hvals = (unsigned*)(wsb + (size_t)HASH_SIZE * 4);         // 2 MB
    int* nbr  = (int*)(wsb + (size_t)HASH_SIZE * 8);                    // 2 MB
    int* ncnt = (int*)(wsb + (size_t)HASH_SIZE * 8 + (size_t)N_PTS * K_NBR * 4);
    unsigned short* w1f = (unsigned short*)((unsigned char*)ncnt + (size_t)N_PTS * 4);
    unsigned short* w2f = w1f + 12288;
    unsigned short* wgf = w2f + 16384;
    float* agg = (float*)(wgf + 16384);                                 // 4 MB
    int* bounds = (int*)((unsigned char*)agg + (size_t)N_PTS * H_DIM * 4);

    hipMemsetAsync(hkeys, 0xFF, (size_t)HASH_SIZE * 8, stream);

    build_hash_kernel<<<E_G / 256, 256, 0, stream>>>(edge_index, hkeys, hvals);
    prep_kernel<<<64, 256, 0, stream>>>(W1, b1, W2, Wg, w1f, w2f, wgf);
    bounds_kernel<<<1, 64, 0, stream>>>(batch, bounds);
    nbr_kernel<<<N_PTS / 4, 256, 0, stream>>>(pos, batch, bounds, nbr, ncnt);
    mlp_kernel<<<N_PTS / 4, 256, 0, stream>>>(x, pos, normal, edge_attr,
                                              hkeys, hvals, nbr, ncnt,
                                              w1f, w2f, b2, agg);
    final_kernel<<<N_PTS / 64, 256, 0, stream>>>(agg, wgf, bg, out);
    tail_kernel<<<(N_PTS * 3 + 255) / 256, 256, 0, stream>>>(pos, batch, out);
}

// Round 4
// 139.846 us; speedup vs baseline: 6.7591x; 1.0964x over previous
//
#include <hip/hip_runtime.h>
#include <math.h>

#define N_PTS   8192
#define F_IN    64
#define D_E     4
#define H_DIM   128
#define OUT_DIM 128
#define K_NBR   64
#define E_G     262144
#define HASH_BITS 19
#define HASH_SIZE (1u << HASH_BITS)
#define HASH_MASK (HASH_SIZE - 1u)
#define HASH_EMPTY 0xFFFFFFFFu
#define CAND_CAP 512

typedef __attribute__((ext_vector_type(8))) short bf16x8;
typedef __attribute__((ext_vector_type(4))) float f32x4;
typedef unsigned int u32;

__device__ __forceinline__ unsigned hash_fn(unsigned key) {
    return (key * 2654435761u) >> (32 - HASH_BITS);
}
__device__ __forceinline__ unsigned short f2bf(float f) {   // RNE f32->bf16
    union { float f; unsigned u; } v; v.f = f;
    unsigned r = v.u + 0x7FFFu + ((v.u >> 16) & 1u);
    return (unsigned short)(r >> 16);
}
__device__ __forceinline__ u32 pack2bf(float a, float b) {
    return (u32)f2bf(a) | ((u32)f2bf(b) << 16);
}
__device__ __forceinline__ bf16x8 cvt8(float4 a, float4 b) {
    union { bf16x8 v; u32 d[4]; } u;
    u.d[0] = pack2bf(a.x, a.y); u.d[1] = pack2bf(a.z, a.w);
    u.d[2] = pack2bf(b.x, b.y); u.d[3] = pack2bf(b.z, b.w);
    return u.v;
}
__device__ __forceinline__ int bperm(int byteaddr, u32 v) {
    return __builtin_amdgcn_ds_bpermute(byteaddr, (int)v);
}

// fast atan2 for y >= 0 (y = |cross| is always >= 0); err ~1e-5 rad
__device__ __forceinline__ float fast_atan2p(float y, float x) {
    float ax = fabsf(x);
    float mn = fminf(ax, y), mx = fmaxf(ax, y);
    float rc = mx > 0.0f ? __builtin_amdgcn_rcpf(mx) : 0.0f;
    float r = mn * rc;
    float t2 = r * r;
    float p = r * (0.99997726f + t2 * (-0.33262347f + t2 * (0.19354346f +
              t2 * (-0.11643287f + t2 * (0.05265332f + t2 * (-0.01172120f))))));
    float a = (y > ax) ? (1.5707963267948966f - p) : p;
    if (x < 0.0f) a = 3.14159265358979f - a;
    return a;
}
__device__ __forceinline__ float angle3(float axv, float ayv, float azv,
                                        float bxv, float byv, float bzv) {
    float cx = ayv * bzv - azv * byv;
    float cy = azv * bxv - axv * bzv;
    float cz = axv * byv - ayv * bxv;
    float cs = cx * cx + cy * cy + cz * cz;
    float cn = cs > 0.0f ? sqrtf(cs) : 0.0f;
    float d  = axv * bxv + ayv * byv + azv * bzv;
    return fast_atan2p(cn, d);   // cn==0&&d==0 -> 0, matches atan2(0,1)
}

// ---------------------------------------------------------------- build hash
__global__ __launch_bounds__(256) void build_hash_kernel(
    const int* __restrict__ ei, unsigned* __restrict__ hkeys,
    unsigned* __restrict__ hvals) {
    int e = blockIdx.x * 256 + threadIdx.x;
    if (e >= E_G) return;
    unsigned key = (unsigned)(ei[e] * N_PTS + ei[E_G + e]);
    unsigned h = hash_fn(key);
    for (;;) {
        unsigned old = atomicCAS(&hkeys[h], HASH_EMPTY, key);
        if (old == HASH_EMPTY || old == key) {
            atomicMin(&hvals[h], (unsigned)e);   // stable-argsort: min edge id wins
            break;
        }
        h = (h + 1u) & HASH_MASK;
    }
}

// ------------------------------ prep: W1/W2/Wg -> bf16 frags (+batch bounds)
__global__ __launch_bounds__(256) void prep_kernel(
    const float* __restrict__ W1, const float* __restrict__ b1,
    const float* __restrict__ W2, const float* __restrict__ Wg,
    const int* __restrict__ batch, int* __restrict__ bounds,
    unsigned short* __restrict__ w1f, unsigned short* __restrict__ w2f,
    unsigned short* __restrict__ wgf) {
    int t = blockIdx.x * 256 + threadIdx.x;
    if (t < 12288) {   // A-frags of W1^T: 3 kt * 8 mt * 64 lane * 8 i
        int i = t & 7, lane = (t >> 3) & 63, mt = (t >> 9) & 7, kt = t >> 12;
        int c1 = mt * 16 + (lane & 15);
        int f  = kt * 32 + (lane >> 4) * 8 + i;
        float v = 0.0f;
        if (f < 72) v = W1[f * H_DIM + c1];
        else if (f == 72) v = b1[c1];   // bias-as-feature
        w1f[t] = f2bf(v);
    }
    if (t < 16384) {   // B-frags: 4 kt * 8 nt * 64 lane * 8 i
        int i = t & 7, lane = (t >> 3) & 63, nt = (t >> 9) & 7, kt = t >> 12;
        int c = nt * 16 + (lane & 15);
        int h = kt * 32 + (lane >> 4) * 8 + i;
        w2f[t] = f2bf(W2[h * H_DIM + c]);
        wgf[t] = f2bf(Wg[h * OUT_DIM + c]);
    }
    if (blockIdx.x == 63 && threadIdx.x <= 8) {   // batch segment bounds
        int q = threadIdx.x;
        int a = 0, c = N_PTS;
        while (a < c) { int m = (a + c) >> 1; if (batch[m] < q) a = m + 1; else c = m; }
        bounds[q] = a;
    }
}

// ----------------------------------------------------------- neighbor search
// wave per point; ballot-compacted candidate collection
__global__ __launch_bounds__(256) void nbr_kernel(
    const float* __restrict__ pos, const int* __restrict__ batch,
    const int* __restrict__ bounds, int* __restrict__ nbr, int* __restrict__ ncnt) {
    __shared__ float s_d2[4][CAND_CAP];
    __shared__ int   s_j[4][CAND_CAP];
    int tid = threadIdx.x, l = tid & 63, w = tid >> 6;
    int i = blockIdx.x * 4 + w;
    int b = batch[i];
    int lo = bounds[b], hi = bounds[b + 1];
    float xi = pos[i * 3 + 0], yi = pos[i * 3 + 1], zi = pos[i * 3 + 2];
    float p2i = xi * xi + yi * yi + zi * zi;
    int cnt = 0;
    for (int j0 = lo; j0 < hi; j0 += 64) {
        int j = j0 + l;
        bool valid = false; float d2 = 0.0f;
        if (j < hi) {
            float xj = pos[j * 3 + 0], yj = pos[j * 3 + 1], zj = pos[j * 3 + 2];
            float p2j = xj * xj + yj * yj + zj * zj;
            float dt  = xi * xj + yi * yj + zi * zj;
            d2 = p2i + p2j - 2.0f * dt;
            valid = d2 <= 4.0f;
        }
        unsigned long long mask = __ballot(valid);
        int pre = __popcll(mask & ((1ull << l) - 1ull));
        if (valid) {
            int pp = cnt + pre;
            if (pp < CAND_CAP) { s_d2[w][pp] = d2; s_j[w][pp] = j; }
        }
        cnt += __popcll(mask);
    }
    if (cnt > CAND_CAP) cnt = CAND_CAP;
    __syncthreads();
    if (cnt <= K_NBR) {
        if (l < cnt) nbr[i * K_NBR + l] = s_j[w][l];
        if (l == 0) ncnt[i] = cnt;
    } else {
        for (int idx = l; idx < cnt; idx += 64) {   // rare: exact top-K by (d2, j)
            float d2 = s_d2[w][idx]; int jj = s_j[w][idx];
            int rank = 0;
            for (int u = 0; u < cnt; ++u) {
                float du = s_d2[w][u]; int ju = s_j[w][u];
                rank += (du < d2) || (du == d2 && ju < jj);
            }
            if (rank < K_NBR) nbr[i * K_NBR + rank] = jj;
        }
        if (l == 0) ncnt[i] = K_NBR;
    }
}

// ---------------------- fused msg + MFMA MLP + max-agg (zero LDS, wave=point)
__global__ __attribute__((amdgpu_flat_work_group_size(256, 256),
                          amdgpu_waves_per_eu(3, 3)))
void mlp_kernel(
    const float* __restrict__ x, const float* __restrict__ pos,
    const float* __restrict__ normal, const float* __restrict__ edge_attr,
    const unsigned* __restrict__ hkeys, const unsigned* __restrict__ hvals,
    const int* __restrict__ nbr, const int* __restrict__ ncnt,
    const unsigned short* __restrict__ w1f, const unsigned short* __restrict__ w2f,
    const float* __restrict__ b2, float* __restrict__ agg) {
    int tid = threadIdx.x;
    int l = tid & 63, w = tid >> 6;
    int p = blockIdx.x * 4 + w;
    int lo16 = l & 15, hi4 = l >> 4;
    int cnt = ncnt[p];
    int jme = (l < cnt) ? nbr[p * K_NBR + l] : -1;

    // ---- ppf + edge_attr for own slot (clamped j; invalid slots masked later)
    int jc = max(jme, 0);
    float pxi = pos[p * 3], pyi = pos[p * 3 + 1], pzi = pos[p * 3 + 2];
    float nxi = normal[p * 3], nyi = normal[p * 3 + 1], nzi = normal[p * 3 + 2];
    float pxj = pos[jc * 3], pyj = pos[jc * 3 + 1], pzj = pos[jc * 3 + 2];
    float nxj = normal[jc * 3], nyj = normal[jc * 3 + 1], nzj = normal[jc * 3 + 2];
    float vx = pxj - pxi, vy = pyj - pyi, vz = pzj - pzi;
    float sq = vx * vx + vy * vy + vz * vz;
    float dd = sq > 0.0f ? sqrtf(sq) : 0.0f;
    float a1 = angle3(nxi, nyi, nzi, vx, vy, vz);
    float a2 = angle3(nxj, nyj, nzj, vx, vy, vz);
    float a3 = angle3(nxi, nyi, nzi, nxj, nyj, nzj);
    unsigned key = (unsigned)(jc * N_PTS + p);
    unsigned hh = hash_fn(key);
    unsigned eidx = E_G;   // sentinel row
    for (;;) {
        unsigned k2 = hkeys[hh];
        if (k2 == key) { eidx = hvals[hh]; break; }
        if (k2 == HASH_EMPTY) break;
        hh = (hh + 1u) & HASH_MASK;
    }
    float4 er = *(const float4*)(edge_attr + (size_t)eidx * D_E);
    u32 pk0 = pack2bf(dd, a1),   pk1 = pack2bf(a2, a3);
    u32 pk2 = pack2bf(er.x, er.y), pk3 = pack2bf(er.z, er.w);

    // ---- layer 1: D1[c1][slot] = W1^T @ msg^T, redistributed to A-frags haf
    bf16x8 haf[4][4];   // [ms][kt-of-layer2]
    int aA = ((hi4 & 1) * 32 + lo16) << 2;
    int aB = aA + (16 << 2);
    int sel = hi4 >> 1;
    #pragma unroll
    for (int pass = 0; pass < 2; ++pass) {
        bf16x8 xf[2][2];    // [nsl][kt]
        bf16x8 ktf[2];      // [nsl]
        #pragma unroll
        for (int nsl = 0; nsl < 2; ++nsl) {
            int ns = pass * 2 + nsl;
            int sa = (ns * 16 + lo16) << 2;
            int j = bperm(sa, (u32)jme);
            const float* xb = x + (size_t)max(j, 0) * F_IN;
            #pragma unroll
            for (int kt = 0; kt < 2; ++kt) {
                float4 a = *(const float4*)(xb + kt * 32 + hi4 * 8);
                float4 b = *(const float4*)(xb + kt * 32 + hi4 * 8 + 4);
                xf[nsl][kt] = cvt8(a, b);
            }
            // kt=2 B-frag: f 64..71 (ppf+eattr, hi4==0), f72 bias=1 (hi4==1), else 0
            u32 q0 = (u32)bperm(sa, pk0);
            u32 q1 = (u32)bperm(sa, pk1);
            u32 q2 = (u32)bperm(sa, pk2);
            u32 q3 = (u32)bperm(sa, pk3);
            union { bf16x8 v; u32 d[4]; } u;
            u.d[0] = hi4 == 0 ? q0 : (hi4 == 1 ? 0x3F80u : 0u);
            u.d[1] = hi4 == 0 ? q1 : 0u;
            u.d[2] = hi4 == 0 ? q2 : 0u;
            u.d[3] = hi4 == 0 ? q3 : 0u;
            ktf[nsl] = u.v;
        }
        #pragma unroll
        for (int mtp = 0; mtp < 4; ++mtp) {
            u32 ph[2][2][2];   // [sub][nsl][dword]
            #pragma unroll
            for (int sub = 0; sub < 2; ++sub) {
                int mt = mtp * 2 + sub;
                bf16x8 af0 = *(const bf16x8*)(w1f + ((0 * 8 + mt) * 64 + l) * 8);
                bf16x8 af1 = *(const bf16x8*)(w1f + ((1 * 8 + mt) * 64 + l) * 8);
                bf16x8 af2 = *(const bf16x8*)(w1f + ((2 * 8 + mt) * 64 + l) * 8);
                #pragma unroll
                for (int nsl = 0; nsl < 2; ++nsl) {
                    f32x4 acc = (f32x4)0.0f;
                    acc = __builtin_amdgcn_mfma_f32_16x16x32_bf16(af0, xf[nsl][0], acc, 0, 0, 0);
                    acc = __builtin_amdgcn_mfma_f32_16x16x32_bf16(af1, xf[nsl][1], acc, 0, 0, 0);
                    acc = __builtin_amdgcn_mfma_f32_16x16x32_bf16(af2, ktf[nsl], acc, 0, 0, 0);
                    ph[sub][nsl][0] = pack2bf(fmaxf(acc[0], 0.0f), fmaxf(acc[1], 0.0f));
                    ph[sub][nsl][1] = pack2bf(fmaxf(acc[2], 0.0f), fmaxf(acc[3], 0.0f));
                }
            }
            // requester (lo16,hi4) needs c1 = mtp*32 + hi4*8 + 0..7 of slot ms*16+lo16:
            // sources = lanes aA (r 0..3) and aB (r 4..7) of mt with mt&1 == hi4>>1
            #pragma unroll
            for (int nsl = 0; nsl < 2; ++nsl) {
                u32 A00 = (u32)bperm(aA, ph[0][nsl][0]);
                u32 A10 = (u32)bperm(aA, ph[0][nsl][1]);
                u32 B00 = (u32)bperm(aB, ph[0][nsl][0]);
                u32 B10 = (u32)bperm(aB, ph[0][nsl][1]);
                u32 A01 = (u32)bperm(aA, ph[1][nsl][0]);
                u32 A11 = (u32)bperm(aA, ph[1][nsl][1]);
                u32 B01 = (u32)bperm(aB, ph[1][nsl][0]);
                u32 B11 = (u32)bperm(aB, ph[1][nsl][1]);
                union { bf16x8 v; u32 d[4]; } u;
                u.d[0] = sel ? A01 : A00;
                u.d[1] = sel ? A11 : A10;
                u.d[2] = sel ? B01 : B00;
                u.d[3] = sel ? B11 : B10;
                haf[pass * 2 + nsl][mtp] = u.v;
            }
        }
    }

    // ---- layer 2: D2[slot][c2] = h1 @ W2 (+b2), relu, masked max over slots
    #pragma unroll
    for (int nt = 0; nt < 8; ++nt) {
        float bb = b2[nt * 16 + lo16];
        f32x4 acc[4];
        #pragma unroll
        for (int ms = 0; ms < 4; ++ms) { f32x4 bv = {bb, bb, bb, bb}; acc[ms] = bv; }
        #pragma unroll
        for (int kt = 0; kt < 4; ++kt) {
            bf16x8 bfr = *(const bf16x8*)(w2f + ((kt * 8 + nt) * 64 + l) * 8);
            #pragma unroll
            for (int ms = 0; ms < 4; ++ms)
                acc[ms] = __builtin_amdgcn_mfma_f32_16x16x32_bf16(haf[ms][kt], bfr, acc[ms], 0, 0, 0);
        }
        float m = -INFINITY;
        #pragma unroll
        for (int ms = 0; ms < 4; ++ms)
            #pragma unroll
            for (int r = 0; r < 4; ++r) {
                int slot = ms * 16 + hi4 * 4 + r;
                float v = fmaxf(acc[ms][r], 0.0f);
                m = fmaxf(m, slot < cnt ? v : -INFINITY);
            }
        m = fmaxf(m, __shfl_xor(m, 16, 64));
        m = fmaxf(m, __shfl_xor(m, 32, 64));
        if (l < 16) agg[(size_t)p * H_DIM + nt * 16 + l] = m;
    }
}

// ------------------- global_nn (MFMA): out = agg @ Wg + bg   (+tail blocks)
__global__ __launch_bounds__(256) void final_kernel(
    const float* __restrict__ agg, const unsigned short* __restrict__ wgf,
    const float* __restrict__ bg, const float* __restrict__ pos,
    const int* __restrict__ batch, float* __restrict__ out) {
    if (blockIdx.x >= N_PTS / 64) {   // tail: pos + batch passthrough
        int idx = (blockIdx.x - N_PTS / 64) * 256 + threadIdx.x;
        if (idx < N_PTS * 3) out[N_PTS * OUT_DIM + idx] = pos[idx];
        if (idx < N_PTS)     out[N_PTS * OUT_DIM + N_PTS * 3 + idx] = (float)batch[idx];
        return;
    }
    int tid = threadIdx.x, l = tid & 63, w = tid >> 6;
    int pbase = blockIdx.x * 64 + w * 16;
    int lo16 = l & 15, hi4 = l >> 4;
    f32x4 acc[8];
    #pragma unroll
    for (int nt = 0; nt < 8; ++nt) {
        float bb = bg[nt * 16 + lo16];
        f32x4 bv = {bb, bb, bb, bb}; acc[nt] = bv;
    }
    #pragma unroll
    for (int kt = 0; kt < 4; ++kt) {
        const float* ab = agg + (size_t)(pbase + lo16) * H_DIM + kt * 32 + hi4 * 8;
        bf16x8 afr = cvt8(*(const float4*)ab, *(const float4*)(ab + 4));
        #pragma unroll
        for (int nt = 0; nt < 8; ++nt) {
            bf16x8 bfr = *(const bf16x8*)(wgf + ((kt * 8 + nt) * 64 + l) * 8);
            acc[nt] = __builtin_amdgcn_mfma_f32_16x16x32_bf16(afr, bfr, acc[nt], 0, 0, 0);
        }
    }
    #pragma unroll
    for (int nt = 0; nt < 8; ++nt)
        #pragma unroll
        for (int r = 0; r < 4; ++r)
            out[(size_t)(pbase + hi4 * 4 + r) * OUT_DIM + nt * 16 + lo16] = acc[nt][r];
}

// ---------------------------------------------------------------------------
extern "C" void kernel_launch(void* const* d_in, const int* in_sizes, int n_in,
                              void* d_out, int out_size, void* d_ws, size_t ws_size,
                              hipStream_t stream) {
    const float* x         = (const float*)d_in[0];
    const float* pos       = (const float*)d_in[1];
    const float* normal    = (const float*)d_in[2];
    const int*   batch     = (const int*)d_in[3];
    const float* edge_attr = (const float*)d_in[4];
    const int*   edge_index= (const int*)d_in[5];
    const float* W1        = (const float*)d_in[6];
    const float* b1        = (const float*)d_in[7];
    const float* W2        = (const float*)d_in[8];
    const float* b2        = (const float*)d_in[9];
    const float* Wg        = (const float*)d_in[10];
    const float* bg        = (const float*)d_in[11];
    float* out = (float*)d_out;

    unsigned char* wsb = (unsigned char*)d_ws;
    unsigned* hkeys = (unsigned*)wsb;                                   // 2 MB
    unsigned* hvals = (unsigned*)(wsb + (size_t)HASH_SIZE * 4);         // 2 MB
    int* nbr  = (int*)(wsb + (size_t)HASH_SIZE * 8);                    // 2 MB
    int* ncnt = (int*)(wsb + (size_t)HASH_SIZE * 8 + (size_t)N_PTS * K_NBR * 4);
    unsigned short* w1f = (unsigned short*)((unsigned char*)ncnt + (size_t)N_PTS * 4);
    unsigned short* w2f = w1f + 12288;
    unsigned short* wgf = w2f + 16384;
    float* agg = (float*)(wgf + 16384);                                 // 4 MB
    int* bounds = (int*)((unsigned char*)agg + (size_t)N_PTS * H_DIM * 4);

    hipMemsetAsync(hkeys, 0xFF, (size_t)HASH_SIZE * 8, stream);

    build_hash_kernel<<<E_G / 256, 256, 0, stream>>>(edge_index, hkeys, hvals);
    prep_kernel<<<64, 256, 0, stream>>>(W1, b1, W2, Wg, batch, bounds, w1f, w2f, wgf);
    nbr_kernel<<<N_PTS / 4, 256, 0, stream>>>(pos, batch, bounds, nbr, ncnt);
    mlp_kernel<<<N_PTS / 4, 256, 0, stream>>>(x, pos, normal, edge_attr,
                                              hkeys, hvals, nbr, ncnt,
                                              w1f, w2f, b2, agg);
    final_kernel<<<N_PTS / 64 + N_PTS / 64, 256, 0, stream>>>(agg, wgf, bg, pos, batch, out);
}

// Round 5
// 124.655 us; speedup vs baseline: 7.5827x; 1.1219x over previous
//
#include <hip/hip_runtime.h>
#include <math.h>

#define N_PTS   8192
#define F_IN    64
#define D_E     4
#define H_DIM   128
#define OUT_DIM 128
#define K_NBR   64
#define E_G     262144
#define HASH_BITS 19
#define HASH_SIZE (1u << HASH_BITS)
#define HASH_MASK (HASH_SIZE - 1u)
#define HASH_EMPTY 0xFFFFFFFFu
#define CAND_CAP 512
#define RSC 40   // chunk-buffer row stride in ushorts (20 dwords, 80 B, 16B-aligned)

typedef __attribute__((ext_vector_type(8))) short bf16x8;
typedef __attribute__((ext_vector_type(4))) float f32x4;
typedef __attribute__((ext_vector_type(4))) unsigned short us4;
typedef unsigned int u32;

__device__ __forceinline__ unsigned hash_fn(unsigned key) {
    return (key * 2654435761u) >> (32 - HASH_BITS);
}
__device__ __forceinline__ unsigned short f2bf(float f) {   // RNE f32->bf16
    union { float f; unsigned u; } v; v.f = f;
    unsigned r = v.u + 0x7FFFu + ((v.u >> 16) & 1u);
    return (unsigned short)(r >> 16);
}
__device__ __forceinline__ u32 pack2bf(float a, float b) {
    return (u32)f2bf(a) | ((u32)f2bf(b) << 16);
}
__device__ __forceinline__ bf16x8 cvt8(float4 a, float4 b) {
    union { bf16x8 v; u32 d[4]; } u;
    u.d[0] = pack2bf(a.x, a.y); u.d[1] = pack2bf(a.z, a.w);
    u.d[2] = pack2bf(b.x, b.y); u.d[3] = pack2bf(b.z, b.w);
    return u.v;
}
__device__ __forceinline__ int bperm(int byteaddr, u32 v) {
    return __builtin_amdgcn_ds_bpermute(byteaddr, (int)v);
}

// fast atan2 for y >= 0 (y = |cross| is always >= 0); err ~1e-5 rad
__device__ __forceinline__ float fast_atan2p(float y, float x) {
    float ax = fabsf(x);
    float mn = fminf(ax, y), mx = fmaxf(ax, y);
    float rc = mx > 0.0f ? __builtin_amdgcn_rcpf(mx) : 0.0f;
    float r = mn * rc;
    float t2 = r * r;
    float p = r * (0.99997726f + t2 * (-0.33262347f + t2 * (0.19354346f +
              t2 * (-0.11643287f + t2 * (0.05265332f + t2 * (-0.01172120f))))));
    float a = (y > ax) ? (1.5707963267948966f - p) : p;
    if (x < 0.0f) a = 3.14159265358979f - a;
    return a;
}
__device__ __forceinline__ float angle3(float axv, float ayv, float azv,
                                        float bxv, float byv, float bzv) {
    float cx = ayv * bzv - azv * byv;
    float cy = azv * bxv - axv * bzv;
    float cz = axv * byv - ayv * bxv;
    float cs = cx * cx + cy * cy + cz * cz;
    float cn = cs > 0.0f ? sqrtf(cs) : 0.0f;
    float d  = axv * bxv + ayv * byv + azv * bzv;
    return fast_atan2p(cn, d);   // cn==0&&d==0 -> 0, matches atan2(0,1)
}

// ---------------------------------------------------------------- build hash
__global__ __launch_bounds__(256) void build_hash_kernel(
    const int* __restrict__ ei, unsigned* __restrict__ hkeys,
    unsigned* __restrict__ hvals) {
    int e = blockIdx.x * 256 + threadIdx.x;
    if (e >= E_G) return;
    unsigned key = (unsigned)(ei[e] * N_PTS + ei[E_G + e]);
    unsigned h = hash_fn(key);
    for (;;) {
        unsigned old = atomicCAS(&hkeys[h], HASH_EMPTY, key);
        if (old == HASH_EMPTY || old == key) {
            atomicMin(&hvals[h], (unsigned)e);   // stable-argsort: min edge id wins
            break;
        }
        h = (h + 1u) & HASH_MASK;
    }
}

// ------------------------------ prep: W1/W2/Wg -> bf16 frags (+batch bounds)
__global__ __launch_bounds__(256) void prep_kernel(
    const float* __restrict__ W1, const float* __restrict__ b1,
    const float* __restrict__ W2, const float* __restrict__ Wg,
    const int* __restrict__ batch, int* __restrict__ bounds,
    unsigned short* __restrict__ w1f, unsigned short* __restrict__ w2f,
    unsigned short* __restrict__ wgf) {
    int t = blockIdx.x * 256 + threadIdx.x;
    if (t < 12288) {   // A-frags of W1^T: 3 kt * 8 mt * 64 lane * 8 i
        int i = t & 7, lane = (t >> 3) & 63, mt = (t >> 9) & 7, kt = t >> 12;
        int c1 = mt * 16 + (lane & 15);
        int f  = kt * 32 + (lane >> 4) * 8 + i;
        float v = 0.0f;
        if (f < 72) v = W1[f * H_DIM + c1];
        else if (f == 72) v = b1[c1];   // bias-as-feature
        w1f[t] = f2bf(v);
    }
    if (t < 16384) {   // B-frags: 4 kt * 8 nt * 64 lane * 8 i
        int i = t & 7, lane = (t >> 3) & 63, nt = (t >> 9) & 7, kt = t >> 12;
        int c = nt * 16 + (lane & 15);
        int h = kt * 32 + (lane >> 4) * 8 + i;
        w2f[t] = f2bf(W2[h * H_DIM + c]);
        wgf[t] = f2bf(Wg[h * OUT_DIM + c]);
    }
    if (blockIdx.x == 63 && threadIdx.x <= 8) {   // batch segment bounds
        int q = threadIdx.x;
        int a = 0, c = N_PTS;
        while (a < c) { int m = (a + c) >> 1; if (batch[m] < q) a = m + 1; else c = m; }
        bounds[q] = a;
    }
}

// ----------------------------------------------------------- neighbor search
// wave per point; ballot-compacted candidate collection
__global__ __launch_bounds__(256) void nbr_kernel(
    const float* __restrict__ pos, const int* __restrict__ batch,
    const int* __restrict__ bounds, int* __restrict__ nbr, int* __restrict__ ncnt) {
    __shared__ float s_d2[4][CAND_CAP];
    __shared__ int   s_j[4][CAND_CAP];
    int tid = threadIdx.x, l = tid & 63, w = tid >> 6;
    int i = blockIdx.x * 4 + w;
    int b = batch[i];
    int lo = bounds[b], hi = bounds[b + 1];
    float xi = pos[i * 3 + 0], yi = pos[i * 3 + 1], zi = pos[i * 3 + 2];
    float p2i = xi * xi + yi * yi + zi * zi;
    int cnt = 0;
    for (int j0 = lo; j0 < hi; j0 += 64) {
        int j = j0 + l;
        bool valid = false; float d2 = 0.0f;
        if (j < hi) {
            float xj = pos[j * 3 + 0], yj = pos[j * 3 + 1], zj = pos[j * 3 + 2];
            float p2j = xj * xj + yj * yj + zj * zj;
            float dt  = xi * xj + yi * yj + zi * zj;
            d2 = p2i + p2j - 2.0f * dt;
            valid = d2 <= 4.0f;
        }
        unsigned long long mask = __ballot(valid);
        int pre = __popcll(mask & ((1ull << l) - 1ull));
        if (valid) {
            int pp = cnt + pre;
            if (pp < CAND_CAP) { s_d2[w][pp] = d2; s_j[w][pp] = j; }
        }
        cnt += __popcll(mask);
    }
    if (cnt > CAND_CAP) cnt = CAND_CAP;
    __syncthreads();
    if (cnt <= K_NBR) {
        if (l < cnt) nbr[i * K_NBR + l] = s_j[w][l];
        if (l == 0) ncnt[i] = cnt;
    } else {
        for (int idx = l; idx < cnt; idx += 64) {   // rare: exact top-K by (d2, j)
            float d2 = s_d2[w][idx]; int jj = s_j[w][idx];
            int rank = 0;
            for (int u = 0; u < cnt; ++u) {
                float du = s_d2[w][u]; int ju = s_j[w][u];
                rank += (du < d2) || (du == d2 && ju < jj);
            }
            if (rank < K_NBR) nbr[i * K_NBR + rank] = jj;
        }
        if (l == 0) ncnt[i] = K_NBR;
    }
}

// ----------- fused msg + MFMA MLP + max-agg (wave=point, LDS chunk reshuffle)
__global__ __launch_bounds__(256)
__attribute__((amdgpu_waves_per_eu(2, 4)))
void mlp_kernel(
    const float* __restrict__ x, const float* __restrict__ pos,
    const float* __restrict__ normal, const float* __restrict__ edge_attr,
    const unsigned* __restrict__ hkeys, const unsigned* __restrict__ hvals,
    const int* __restrict__ nbr, const int* __restrict__ ncnt,
    const unsigned short* __restrict__ w1f, const unsigned short* __restrict__ w2f,
    const float* __restrict__ b2, float* __restrict__ agg) {
    // per-wave chunk buffer: 32 slot-rows x 32 c1-cols, stride RSC=40 ushorts
    __shared__ unsigned short chunkb[4][32 * RSC];   // 10,240 B total
    int tid = threadIdx.x;
    int l = tid & 63, w = tid >> 6;
    int p = blockIdx.x * 4 + w;
    int lo16 = l & 15, hi4 = l >> 4;
    int cnt = ncnt[p];
    int jme = (l < cnt) ? nbr[p * K_NBR + l] : -1;
    unsigned short* cb = chunkb[w];

    // ---- ppf + edge_attr for own slot (clamped j; invalid slots masked later)
    int jc = max(jme, 0);
    float pxi = pos[p * 3], pyi = pos[p * 3 + 1], pzi = pos[p * 3 + 2];
    float nxi = normal[p * 3], nyi = normal[p * 3 + 1], nzi = normal[p * 3 + 2];
    float pxj = pos[jc * 3], pyj = pos[jc * 3 + 1], pzj = pos[jc * 3 + 2];
    float nxj = normal[jc * 3], nyj = normal[jc * 3 + 1], nzj = normal[jc * 3 + 2];
    float vx = pxj - pxi, vy = pyj - pyi, vz = pzj - pzi;
    float sq = vx * vx + vy * vy + vz * vz;
    float dd = sq > 0.0f ? sqrtf(sq) : 0.0f;
    float a1 = angle3(nxi, nyi, nzi, vx, vy, vz);
    float a2 = angle3(nxj, nyj, nzj, vx, vy, vz);
    float a3 = angle3(nxi, nyi, nzi, nxj, nyj, nzj);
    unsigned key = (unsigned)(jc * N_PTS + p);
    unsigned hh = hash_fn(key);
    unsigned eidx = E_G;   // sentinel row
    for (;;) {
        unsigned k2 = hkeys[hh];
        if (k2 == key) { eidx = hvals[hh]; break; }
        if (k2 == HASH_EMPTY) break;
        hh = (hh + 1u) & HASH_MASK;
    }
    float4 er = *(const float4*)(edge_attr + (size_t)eidx * D_E);
    u32 pk0 = pack2bf(dd, a1),   pk1 = pack2bf(a2, a3);
    u32 pk2 = pack2bf(er.x, er.y), pk3 = pack2bf(er.z, er.w);

    // ---- layer 1: D1[c1][slot] = W1^T @ msg^T; reshuffle via LDS chunk to
    //      layer-2 A-frags haf[ms][kt]
    bf16x8 haf[4][4];   // [ms][kt]
    #pragma unroll
    for (int pass = 0; pass < 2; ++pass) {
        bf16x8 xf[2][2];    // [nsl][kt]
        bf16x8 ktf[2];      // [nsl]
        #pragma unroll
        for (int nsl = 0; nsl < 2; ++nsl) {
            int ns = pass * 2 + nsl;
            int sa = (ns * 16 + lo16) << 2;
            int j = bperm(sa, (u32)jme);
            const float* xb = x + (size_t)max(j, 0) * F_IN;
            #pragma unroll
            for (int kt = 0; kt < 2; ++kt) {
                float4 a = *(const float4*)(xb + kt * 32 + hi4 * 8);
                float4 b = *(const float4*)(xb + kt * 32 + hi4 * 8 + 4);
                xf[nsl][kt] = cvt8(a, b);
            }
            // kt=2 B-frag: f 64..71 (ppf+eattr, hi4==0), f72 bias=1 (hi4==1), else 0
            u32 q0 = (u32)bperm(sa, pk0);
            u32 q1 = (u32)bperm(sa, pk1);
            u32 q2 = (u32)bperm(sa, pk2);
            u32 q3 = (u32)bperm(sa, pk3);
            union { bf16x8 v; u32 d[4]; } u;
            u.d[0] = hi4 == 0 ? q0 : (hi4 == 1 ? 0x3F80u : 0u);
            u.d[1] = hi4 == 0 ? q1 : 0u;
            u.d[2] = hi4 == 0 ? q2 : 0u;
            u.d[3] = hi4 == 0 ? q3 : 0u;
            ktf[nsl] = u.v;
        }
        #pragma unroll
        for (int mtp = 0; mtp < 4; ++mtp) {
            // compute quadrant (c1 in [mtp*32, mtp*32+32), slots of this pass)
            #pragma unroll
            for (int sub = 0; sub < 2; ++sub) {
                int mt = mtp * 2 + sub;
                bf16x8 af0 = *(const bf16x8*)(w1f + ((0 * 8 + mt) * 64 + l) * 8);
                bf16x8 af1 = *(const bf16x8*)(w1f + ((1 * 8 + mt) * 64 + l) * 8);
                bf16x8 af2 = *(const bf16x8*)(w1f + ((2 * 8 + mt) * 64 + l) * 8);
                #pragma unroll
                for (int nsl = 0; nsl < 2; ++nsl) {
                    f32x4 acc = (f32x4)0.0f;
                    acc = __builtin_amdgcn_mfma_f32_16x16x32_bf16(af0, xf[nsl][0], acc, 0, 0, 0);
                    acc = __builtin_amdgcn_mfma_f32_16x16x32_bf16(af1, xf[nsl][1], acc, 0, 0, 0);
                    acc = __builtin_amdgcn_mfma_f32_16x16x32_bf16(af2, ktf[nsl], acc, 0, 0, 0);
                    // relu + pack; C-lane holds c1 = mt*16+hi4*4+r of slot-col lo16
                    us4 o;
                    o[0] = f2bf(fmaxf(acc[0], 0.0f));
                    o[1] = f2bf(fmaxf(acc[1], 0.0f));
                    o[2] = f2bf(fmaxf(acc[2], 0.0f));
                    o[3] = f2bf(fmaxf(acc[3], 0.0f));
                    *(us4*)(cb + (nsl * 16 + lo16) * RSC + sub * 16 + hi4 * 4) = o;
                }
            }
            // read back as layer-2 A-frags: row=slot (lane&15), k=c1 (hi4*8+i)
            #pragma unroll
            for (int nsl = 0; nsl < 2; ++nsl)
                haf[pass * 2 + nsl][mtp] =
                    *(const bf16x8*)(cb + (nsl * 16 + lo16) * RSC + hi4 * 8);
        }
    }

    // ---- layer 2: D2[slot][c2] = h1 @ W2 (+b2), relu, masked max over slots
    #pragma unroll
    for (int nt = 0; nt < 8; ++nt) {
        float bb = b2[nt * 16 + lo16];
        f32x4 acc[4];
        #pragma unroll
        for (int ms = 0; ms < 4; ++ms) { f32x4 bv = {bb, bb, bb, bb}; acc[ms] = bv; }
        #pragma unroll
        for (int kt = 0; kt < 4; ++kt) {
            bf16x8 bfr = *(const bf16x8*)(w2f + ((kt * 8 + nt) * 64 + l) * 8);
            #pragma unroll
            for (int ms = 0; ms < 4; ++ms)
                acc[ms] = __builtin_amdgcn_mfma_f32_16x16x32_bf16(haf[ms][kt], bfr, acc[ms], 0, 0, 0);
        }
        float m = -INFINITY;
        #pragma unroll
        for (int ms = 0; ms < 4; ++ms)
            #pragma unroll
            for (int r = 0; r < 4; ++r) {
                int slot = ms * 16 + hi4 * 4 + r;
                float v = fmaxf(acc[ms][r], 0.0f);
                m = fmaxf(m, slot < cnt ? v : -INFINITY);
            }
        m = fmaxf(m, __shfl_xor(m, 16, 64));
        m = fmaxf(m, __shfl_xor(m, 32, 64));
        if (l < 16) agg[(size_t)p * H_DIM + nt * 16 + l] = m;
    }
}

// ------------------- global_nn (MFMA): out = agg @ Wg + bg   (+tail blocks)
__global__ __launch_bounds__(256) void final_kernel(
    const float* __restrict__ agg, const unsigned short* __restrict__ wgf,
    const float* __restrict__ bg, const float* __restrict__ pos,
    const int* __restrict__ batch, float* __restrict__ out) {
    if (blockIdx.x >= N_PTS / 64) {   // tail: pos + batch passthrough
        int idx = (blockIdx.x - N_PTS / 64) * 256 + threadIdx.x;
        if (idx < N_PTS * 3) out[N_PTS * OUT_DIM + idx] = pos[idx];
        if (idx < N_PTS)     out[N_PTS * OUT_DIM + N_PTS * 3 + idx] = (float)batch[idx];
        return;
    }
    int tid = threadIdx.x, l = tid & 63, w = tid >> 6;
    int pbase = blockIdx.x * 64 + w * 16;
    int lo16 = l & 15, hi4 = l >> 4;
    f32x4 acc[8];
    #pragma unroll
    for (int nt = 0; nt < 8; ++nt) {
        float bb = bg[nt * 16 + lo16];
        f32x4 bv = {bb, bb, bb, bb}; acc[nt] = bv;
    }
    #pragma unroll
    for (int kt = 0; kt < 4; ++kt) {
        const float* ab = agg + (size_t)(pbase + lo16) * H_DIM + kt * 32 + hi4 * 8;
        bf16x8 afr = cvt8(*(const float4*)ab, *(const float4*)(ab + 4));
        #pragma unroll
        for (int nt = 0; nt < 8; ++nt) {
            bf16x8 bfr = *(const bf16x8*)(wgf + ((kt * 8 + nt) * 64 + l) * 8);
            acc[nt] = __builtin_amdgcn_mfma_f32_16x16x32_bf16(afr, bfr, acc[nt], 0, 0, 0);
        }
    }
    #pragma unroll
    for (int nt = 0; nt < 8; ++nt)
        #pragma unroll
        for (int r = 0; r < 4; ++r)
            out[(size_t)(pbase + hi4 * 4 + r) * OUT_DIM + nt * 16 + lo16] = acc[nt][r];
}

// ---------------------------------------------------------------------------
extern "C" void kernel_launch(void* const* d_in, const int* in_sizes, int n_in,
                              void* d_out, int out_size, void* d_ws, size_t ws_size,
                              hipStream_t stream) {
    const float* x         = (const float*)d_in[0];
    const float* pos       = (const float*)d_in[1];
    const float* normal    = (const float*)d_in[2];
    const int*   batch     = (const int*)d_in[3];
    const float* edge_attr = (const float*)d_in[4];
    const int*   edge_index= (const int*)d_in[5];
    const float* W1        = (const float*)d_in[6];
    const float* b1        = (const float*)d_in[7];
    const float* W2        = (const float*)d_in[8];
    const float* b2        = (const float*)d_in[9];
    const float* Wg        = (const float*)d_in[10];
    const float* bg        = (const float*)d_in[11];
    float* out = (float*)d_out;

    unsigned char* wsb = (unsigned char*)d_ws;
    unsigned* hkeys = (unsigned*)wsb;                                   // 2 MB
    unsigned* hvals = (unsigned*)(wsb + (size_t)HASH_SIZE * 4);         // 2 MB
    int* nbr  = (int*)(wsb + (size_t)HASH_SIZE * 8);                    // 2 MB
    int* ncnt = (int*)(wsb + (size_t)HASH_SIZE * 8 + (size_t)N_PTS * K_NBR * 4);
    unsigned short* w1f = (unsigned short*)((unsigned char*)ncnt + (size_t)N_PTS * 4);
    unsigned short* w2f = w1f + 12288;
    unsigned short* wgf = w2f + 16384;
    float* agg = (float*)(wgf + 16384);                                 // 4 MB
    int* bounds = (int*)((unsigned char*)agg + (size_t)N_PTS * H_DIM * 4);

    hipMemsetAsync(hkeys, 0xFF, (size_t)HASH_SIZE * 8, stream);

    build_hash_kernel<<<E_G / 256, 256, 0, stream>>>(edge_index, hkeys, hvals);
    prep_kernel<<<64, 256, 0, stream>>>(W1, b1, W2, Wg, batch, bounds, w1f, w2f, wgf);
    nbr_kernel<<<N_PTS / 4, 256, 0, stream>>>(pos, batch, bounds, nbr, ncnt);
    mlp_kernel<<<N_PTS / 4, 256, 0, stream>>>(x, pos, normal, edge_attr,
                                              hkeys, hvals, nbr, ncnt,
                                              w1f, w2f, b2, agg);
    final_kernel<<<N_PTS / 64 + N_PTS / 64, 256, 0, stream>>>(agg, wgf, bg, pos, batch, out);
}

// Round 6
// 121.374 us; speedup vs baseline: 7.7878x; 1.0270x over previous
//
#include <hip/hip_runtime.h>
#include <math.h>

#define N_PTS   8192
#define F_IN    64
#define D_E     4
#define H_DIM   128
#define OUT_DIM 128
#define K_NBR   64
#define E_G     262144
#define HASH_BITS 19
#define HASH_SIZE (1u << HASH_BITS)
#define HASH_MASK (HASH_SIZE - 1u)
#define HASH_EMPTY 0xFFFFFFFFu
#define CAND 256
#define RSC 40   // chunk row stride in ushorts (80 B)

typedef __attribute__((ext_vector_type(8))) short bf16x8;
typedef __attribute__((ext_vector_type(4))) float f32x4;
typedef unsigned int u32;

__device__ __forceinline__ unsigned hash_fn(unsigned key) {
    return (key * 2654435761u) >> (32 - HASH_BITS);
}
__device__ __forceinline__ unsigned short f2bf(float f) {   // RNE f32->bf16
    union { float f; unsigned u; } v; v.f = f;
    unsigned r = v.u + 0x7FFFu + ((v.u >> 16) & 1u);
    return (unsigned short)(r >> 16);
}
__device__ __forceinline__ u32 pack2bf(float a, float b) {  // RNE pair
    return (u32)f2bf(a) | ((u32)f2bf(b) << 16);
}
// truncation pack: D = {hi16(b), hi16(a)} in ONE v_perm_b32
__device__ __forceinline__ u32 pack2t(float a, float b) {
    return __builtin_amdgcn_perm(__float_as_uint(b), __float_as_uint(a), 0x07060302u);
}
__device__ __forceinline__ bf16x8 cvt8t(float4 a, float4 b) {
    union { bf16x8 v; u32 d[4]; } u;
    u.d[0] = pack2t(a.x, a.y); u.d[1] = pack2t(a.z, a.w);
    u.d[2] = pack2t(b.x, b.y); u.d[3] = pack2t(b.z, b.w);
    return u.v;
}

// fast atan2 for y >= 0; err ~1e-5 rad
__device__ __forceinline__ float fast_atan2p(float y, float x) {
    float ax = fabsf(x);
    float mn = fminf(ax, y), mx = fmaxf(ax, y);
    float rc = mx > 0.0f ? __builtin_amdgcn_rcpf(mx) : 0.0f;
    float r = mn * rc;
    float t2 = r * r;
    float p = r * (0.99997726f + t2 * (-0.33262347f + t2 * (0.19354346f +
              t2 * (-0.11643287f + t2 * (0.05265332f + t2 * (-0.01172120f))))));
    float a = (y > ax) ? (1.5707963267948966f - p) : p;
    if (x < 0.0f) a = 3.14159265358979f - a;
    return a;
}
__device__ __forceinline__ float angle3(float axv, float ayv, float azv,
                                        float bxv, float byv, float bzv) {
    float cx = ayv * bzv - azv * byv;
    float cy = azv * bxv - axv * bzv;
    float cz = axv * byv - ayv * bxv;
    float cs = cx * cx + cy * cy + cz * cz;
    float cn = cs > 0.0f ? sqrtf(cs) : 0.0f;
    float d  = axv * bxv + ayv * byv + azv * bzv;
    return fast_atan2p(cn, d);   // cn==0&&d==0 -> 0 == atan2(0,1)
}

// ------------------- setup: hash build (blocks 0..1023) + weight frags/bounds
__global__ __launch_bounds__(256) void setup_kernel(
    const int* __restrict__ ei, unsigned* __restrict__ hkeys,
    unsigned* __restrict__ hvals,
    const float* __restrict__ W1, const float* __restrict__ b1,
    const float* __restrict__ W2, const float* __restrict__ Wg,
    const int* __restrict__ batch, int* __restrict__ bounds,
    unsigned short* __restrict__ w1f, unsigned short* __restrict__ w2f,
    unsigned short* __restrict__ wgf) {
    int gb = blockIdx.x;
    if (gb < E_G / 256) {
        int e = gb * 256 + threadIdx.x;
        unsigned key = (unsigned)(ei[e] * N_PTS + ei[E_G + e]);
        unsigned h = hash_fn(key);
        for (;;) {
            unsigned old = atomicCAS(&hkeys[h], HASH_EMPTY, key);
            if (old == HASH_EMPTY || old == key) {
                atomicMin(&hvals[h], (unsigned)e);   // stable: min edge id wins
                break;
            }
            h = (h + 1u) & HASH_MASK;
        }
        return;
    }
    int t = (gb - E_G / 256) * 256 + threadIdx.x;
    if (t < 12288) {   // A-frags of W1^T: 3 kt * 8 mt * 64 lane * 8 i
        int i = t & 7, lane = (t >> 3) & 63, mt = (t >> 9) & 7, kt = t >> 12;
        int c1 = mt * 16 + (lane & 15);
        int f  = kt * 32 + (lane >> 4) * 8 + i;
        float v = 0.0f;
        if (f < 72) v = W1[f * H_DIM + c1];
        else if (f == 72) v = b1[c1];   // bias-as-feature
        w1f[t] = f2bf(v);
    }
    if (t < 16384) {   // B-frags: 4 kt * 8 nt * 64 lane * 8 i
        int i = t & 7, lane = (t >> 3) & 63, nt = (t >> 9) & 7, kt = t >> 12;
        int c = nt * 16 + (lane & 15);
        int h = kt * 32 + (lane >> 4) * 8 + i;
        w2f[t] = f2bf(W2[h * H_DIM + c]);
        wgf[t] = f2bf(Wg[h * OUT_DIM + c]);
    }
    if (t >= 16384 - 256 && threadIdx.x <= 8) {   // batch segment bounds
        int q = threadIdx.x;
        int a = 0, c = N_PTS;
        while (a < c) { int m = (a + c) >> 1; if (batch[m] < q) a = m + 1; else c = m; }
        bounds[q] = a;
    }
}

// --- fused radius-search + msg + MFMA MLP + max-agg (wave = point, no barriers)
// per-wave 4 KB LDS: [0,256) nbrlist(64 int) | [256,1280) pkrow(64x16B)
//                    | [1280,3840) chunk(32xRSC us)  [phase-A overlay: d2s/js]
__global__ __launch_bounds__(256)
__attribute__((amdgpu_waves_per_eu(4, 8)))
void mlp_kernel(
    const float* __restrict__ x, const float* __restrict__ pos,
    const float* __restrict__ normal, const float* __restrict__ edge_attr,
    const unsigned* __restrict__ hkeys, const unsigned* __restrict__ hvals,
    const int* __restrict__ batch, const int* __restrict__ bounds,
    const unsigned short* __restrict__ w1f, const unsigned short* __restrict__ w2f,
    const float* __restrict__ b2, float* __restrict__ agg) {
    __shared__ __align__(16) unsigned char smem[4][4096];
    int tid = threadIdx.x;
    int l = tid & 63, w = tid >> 6;
    int p = blockIdx.x * 4 + w;
    int lo16 = l & 15, hi4 = l >> 4;
    unsigned char* wbase = smem[w];
    int*   nbrlist = (int*)wbase;
    int*   pkrow   = (int*)(wbase + 256);
    float* d2s     = (float*)(wbase + 1280);
    int*   js      = (int*)(wbase + 2304);
    unsigned short* cb = (unsigned short*)(wbase + 1280);

    // ================= phase A: radius ball query (K=64, r^2=4, per batch) ===
    float pxi = pos[p * 3], pyi = pos[p * 3 + 1], pzi = pos[p * 3 + 2];
    float p2i = pxi * pxi + pyi * pyi + pzi * pzi;
    {
        int b = batch[p];
        int lo = bounds[b], hi = bounds[b + 1];
        int cnt0 = 0;
        for (int j0 = lo; j0 < hi; j0 += 64) {
            int j = j0 + l;
            bool valid = false; float d2 = 0.0f;
            if (j < hi) {
                float xj = pos[j * 3], yj = pos[j * 3 + 1], zj = pos[j * 3 + 2];
                float p2j = xj * xj + yj * yj + zj * zj;
                float dt  = pxi * xj + pyi * yj + pzi * zj;
                d2 = p2i + p2j - 2.0f * dt;   // ref formula; self -> exactly 0
                valid = d2 <= 4.0f;
            }
            unsigned long long mask = __ballot(valid);
            int pp = cnt0 + __popcll(mask & ((1ull << l) - 1ull));
            if (valid && pp < CAND) { d2s[pp] = d2; js[pp] = j; }
            cnt0 += __popcll(mask);
        }
        if (cnt0 > CAND) cnt0 = CAND;
        if (cnt0 <= K_NBR) {
            nbrlist[l] = (l < cnt0) ? js[l] : -1;
        } else {
            // rare: exact top-K by (d2 asc, index asc) == jax top_k tie-break
            for (int idx = l; idx < cnt0; idx += 64) {
                float d2 = d2s[idx]; int jj = js[idx];
                int rank = 0;
                for (int u = 0; u < cnt0; ++u)
                    rank += (d2s[u] < d2) || (d2s[u] == d2 && js[u] < jj);
                if (rank < K_NBR) nbrlist[rank] = jj;
            }
            cnt0 = K_NBR;
        }
        // stash cnt in a register for the rest
        #define CNT cnt
        int cnt = cnt0;

    // ================= phase B: ppf + edge_attr for own slot =================
    int jme = nbrlist[l];
    int jc = max(jme, 0);
    float nxi = normal[p * 3], nyi = normal[p * 3 + 1], nzi = normal[p * 3 + 2];
    float pxj = pos[jc * 3], pyj = pos[jc * 3 + 1], pzj = pos[jc * 3 + 2];
    float nxj = normal[jc * 3], nyj = normal[jc * 3 + 1], nzj = normal[jc * 3 + 2];
    float vx = pxj - pxi, vy = pyj - pyi, vz = pzj - pzi;
    float sq = vx * vx + vy * vy + vz * vz;
    float dd = sq > 0.0f ? sqrtf(sq) : 0.0f;
    float a1 = angle3(nxi, nyi, nzi, vx, vy, vz);
    float a2 = angle3(nxj, nyj, nzj, vx, vy, vz);
    float a3 = angle3(nxi, nyi, nzi, nxj, nyj, nzj);
    unsigned key = (unsigned)(jc * N_PTS + p);
    unsigned hh = hash_fn(key);
    unsigned eidx = E_G;   // sentinel row
    for (;;) {
        unsigned k2 = hkeys[hh];
        if (k2 == key) { eidx = hvals[hh]; break; }
        if (k2 == HASH_EMPTY) break;
        hh = (hh + 1u) & HASH_MASK;
    }
    float4 er = *(const float4*)(edge_attr + (size_t)eidx * D_E);
    int4 pk;
    pk.x = (int)pack2bf(dd, a1);   pk.y = (int)pack2bf(a2, a3);
    pk.z = (int)pack2bf(er.x, er.y); pk.w = (int)pack2bf(er.z, er.w);
    ((int4*)pkrow)[l] = pk;

    // ===== layer 1: D1[c1][slot] = W1^T @ msg^T; LDS-chunk reshuffle to haf ==
    bf16x8 haf[4][4];   // [ms][kt]
    #pragma unroll
    for (int pass = 0; pass < 2; ++pass) {
        bf16x8 xf[2][2];    // [nsl][kt]
        bf16x8 ktf[2];
        #pragma unroll
        for (int nsl = 0; nsl < 2; ++nsl) {
            int slot = (pass * 2 + nsl) * 16 + lo16;
            int j = nbrlist[slot];
            const float* xb = x + (size_t)max(j, 0) * F_IN;
            #pragma unroll
            for (int kt = 0; kt < 2; ++kt) {
                float4 a = *(const float4*)(xb + kt * 32 + hi4 * 8);
                float4 b = *(const float4*)(xb + kt * 32 + hi4 * 8 + 4);
                xf[nsl][kt] = cvt8t(a, b);
            }
            // kt=2 B-frag: f64..71 = ppf+eattr (hi4==0); f72 bias=1 (hi4==1)
            int4 q = ((const int4*)pkrow)[slot];
            union { bf16x8 v; u32 d[4]; } u;
            u.d[0] = hi4 == 0 ? (u32)q.x : (hi4 == 1 ? 0x3F80u : 0u);
            u.d[1] = hi4 == 0 ? (u32)q.y : 0u;
            u.d[2] = hi4 == 0 ? (u32)q.z : 0u;
            u.d[3] = hi4 == 0 ? (u32)q.w : 0u;
            ktf[nsl] = u.v;
        }
        #pragma unroll
        for (int mtp = 0; mtp < 4; ++mtp) {
            #pragma unroll
            for (int sub = 0; sub < 2; ++sub) {
                int mt = mtp * 2 + sub;
                bf16x8 af0 = *(const bf16x8*)(w1f + ((0 * 8 + mt) * 64 + l) * 8);
                bf16x8 af1 = *(const bf16x8*)(w1f + ((1 * 8 + mt) * 64 + l) * 8);
                bf16x8 af2 = *(const bf16x8*)(w1f + ((2 * 8 + mt) * 64 + l) * 8);
                #pragma unroll
                for (int nsl = 0; nsl < 2; ++nsl) {
                    f32x4 acc = (f32x4)0.0f;
                    acc = __builtin_amdgcn_mfma_f32_16x16x32_bf16(af0, xf[nsl][0], acc, 0, 0, 0);
                    acc = __builtin_amdgcn_mfma_f32_16x16x32_bf16(af1, xf[nsl][1], acc, 0, 0, 0);
                    acc = __builtin_amdgcn_mfma_f32_16x16x32_bf16(af2, ktf[nsl], acc, 0, 0, 0);
                    // relu + 2x v_perm pack; lane holds c1=mt*16+hi4*4+r, slot-col lo16
                    uint2 o;
                    o.x = pack2t(fmaxf(acc[0], 0.0f), fmaxf(acc[1], 0.0f));
                    o.y = pack2t(fmaxf(acc[2], 0.0f), fmaxf(acc[3], 0.0f));
                    *(uint2*)(cb + (nsl * 16 + lo16) * RSC + sub * 16 + hi4 * 4) = o;
                }
            }
            // read back as layer-2 A-frags: row=slot(lane&15), k=c1(hi4*8+i)
            #pragma unroll
            for (int nsl = 0; nsl < 2; ++nsl)
                haf[pass * 2 + nsl][mtp] =
                    *(const bf16x8*)(cb + (nsl * 16 + lo16) * RSC + hi4 * 8);
        }
    }

    // ===== layer 2: D2[slot][c2] = h1 @ W2 (+b2); masked relu-max over slots =
    #pragma unroll
    for (int nt = 0; nt < 8; ++nt) {
        float bb = b2[nt * 16 + lo16];
        f32x4 acc[4];
        #pragma unroll
        for (int ms = 0; ms < 4; ++ms) { f32x4 bv = {bb, bb, bb, bb}; acc[ms] = bv; }
        #pragma unroll
        for (int kt = 0; kt < 4; ++kt) {
            bf16x8 bfr = *(const bf16x8*)(w2f + ((kt * 8 + nt) * 64 + l) * 8);
            #pragma unroll
            for (int ms = 0; ms < 4; ++ms)
                acc[ms] = __builtin_amdgcn_mfma_f32_16x16x32_bf16(haf[ms][kt], bfr, acc[ms], 0, 0, 0);
        }
        // m starts at 0: max over valid of relu(h) == max(0, max over valid h)
        // (self slot always valid)
        float m = 0.0f;
        #pragma unroll
        for (int ms = 0; ms < 4; ++ms)
            #pragma unroll
            for (int r = 0; r < 4; ++r) {
                int slot = ms * 16 + hi4 * 4 + r;
                m = fmaxf(m, slot < cnt ? acc[ms][r] : 0.0f);
            }
        m = fmaxf(m, __shfl_xor(m, 16, 64));
        m = fmaxf(m, __shfl_xor(m, 32, 64));
        if (l < 16) agg[(size_t)p * H_DIM + nt * 16 + l] = m;
    }
    }   // scope of cnt
}

// ------------------- global_nn (MFMA): out = agg @ Wg + bg   (+tail blocks)
__global__ __launch_bounds__(256) void final_kernel(
    const float* __restrict__ agg, const unsigned short* __restrict__ wgf,
    const float* __restrict__ bg, const float* __restrict__ pos,
    const int* __restrict__ batch, float* __restrict__ out) {
    if (blockIdx.x >= N_PTS / 64) {   // tail: pos + batch passthrough
        int idx = (blockIdx.x - N_PTS / 64) * 256 + threadIdx.x;
        if (idx < N_PTS * 3) out[N_PTS * OUT_DIM + idx] = pos[idx];
        if (idx < N_PTS)     out[N_PTS * OUT_DIM + N_PTS * 3 + idx] = (float)batch[idx];
        return;
    }
    int tid = threadIdx.x, l = tid & 63, w = tid >> 6;
    int pbase = blockIdx.x * 64 + w * 16;
    int lo16 = l & 15, hi4 = l >> 4;
    f32x4 acc[8];
    #pragma unroll
    for (int nt = 0; nt < 8; ++nt) {
        float bb = bg[nt * 16 + lo16];
        f32x4 bv = {bb, bb, bb, bb}; acc[nt] = bv;
    }
    #pragma unroll
    for (int kt = 0; kt < 4; ++kt) {
        const float* ab = agg + (size_t)(pbase + lo16) * H_DIM + kt * 32 + hi4 * 8;
        bf16x8 afr = cvt8t(*(const float4*)ab, *(const float4*)(ab + 4));
        #pragma unroll
        for (int nt = 0; nt < 8; ++nt) {
            bf16x8 bfr = *(const bf16x8*)(wgf + ((kt * 8 + nt) * 64 + l) * 8);
            acc[nt] = __builtin_amdgcn_mfma_f32_16x16x32_bf16(afr, bfr, acc[nt], 0, 0, 0);
        }
    }
    #pragma unroll
    for (int nt = 0; nt < 8; ++nt)
        #pragma unroll
        for (int r = 0; r < 4; ++r)
            out[(size_t)(pbase + hi4 * 4 + r) * OUT_DIM + nt * 16 + lo16] = acc[nt][r];
}

// ---------------------------------------------------------------------------
extern "C" void kernel_launch(void* const* d_in, const int* in_sizes, int n_in,
                              void* d_out, int out_size, void* d_ws, size_t ws_size,
                              hipStream_t stream) {
    const float* x         = (const float*)d_in[0];
    const float* pos       = (const float*)d_in[1];
    const float* normal    = (const float*)d_in[2];
    const int*   batch     = (const int*)d_in[3];
    const float* edge_attr = (const float*)d_in[4];
    const int*   edge_index= (const int*)d_in[5];
    const float* W1        = (const float*)d_in[6];
    const float* b1        = (const float*)d_in[7];
    const float* W2        = (const float*)d_in[8];
    const float* b2        = (const float*)d_in[9];
    const float* Wg        = (const float*)d_in[10];
    const float* bg        = (const float*)d_in[11];
    float* out = (float*)d_out;

    unsigned char* wsb = (unsigned char*)d_ws;
    unsigned* hkeys = (unsigned*)wsb;                                   // 2 MB
    unsigned* hvals = (unsigned*)(wsb + (size_t)HASH_SIZE * 4);         // 2 MB
    unsigned short* w1f = (unsigned short*)(wsb + (size_t)HASH_SIZE * 8);
    unsigned short* w2f = w1f + 12288;
    unsigned short* wgf = w2f + 16384;
    float* agg = (float*)(wgf + 16384);                                 // 4 MB
    int* bounds = (int*)((unsigned char*)agg + (size_t)N_PTS * H_DIM * 4);

    hipMemsetAsync(hkeys, 0xFF, (size_t)HASH_SIZE * 8, stream);

    setup_kernel<<<E_G / 256 + 64, 256, 0, stream>>>(
        edge_index, hkeys, hvals, W1, b1, W2, Wg, batch, bounds, w1f, w2f, wgf);
    mlp_kernel<<<N_PTS / 4, 256, 0, stream>>>(x, pos, normal, edge_attr,
                                              hkeys, hvals, batch, bounds,
                                              w1f, w2f, b2, agg);
    final_kernel<<<N_PTS / 64 + N_PTS / 64, 256, 0, stream>>>(agg, wgf, bg, pos, batch, out);
}

// Round 7
// 113.680 us; speedup vs baseline: 8.3148x; 1.0677x over previous
//
#include <hip/hip_runtime.h>
#include <math.h>

#define N_PTS   8192
#define F_IN    64
#define D_E     4
#define H_DIM   128
#define OUT_DIM 128
#define K_NBR   64
#define E_G     262144
#define HASH_BITS 19
#define HASH_SIZE (1u << HASH_BITS)
#define HASH_MASK (HASH_SIZE - 1u)
#define HASH_EMPTY 0xFFFFFFFFu
#define CAND 256
#define RSC 40   // chunk row stride in ushorts (80 B)

typedef __attribute__((ext_vector_type(8))) short bf16x8;
typedef __attribute__((ext_vector_type(4))) float f32x4;
typedef unsigned int u32;

__device__ __forceinline__ unsigned hash_fn(unsigned key) {
    return (key * 2654435761u) >> (32 - HASH_BITS);
}
__device__ __forceinline__ unsigned short f2bf(float f) {   // RNE f32->bf16
    union { float f; unsigned u; } v; v.f = f;
    unsigned r = v.u + 0x7FFFu + ((v.u >> 16) & 1u);
    return (unsigned short)(r >> 16);
}
__device__ __forceinline__ u32 pack2bf(float a, float b) {  // RNE pair
    return (u32)f2bf(a) | ((u32)f2bf(b) << 16);
}
// truncation pack: D = {hi16(b), hi16(a)} in ONE v_perm_b32
__device__ __forceinline__ u32 pack2t(float a, float b) {
    return __builtin_amdgcn_perm(__float_as_uint(b), __float_as_uint(a), 0x07060302u);
}

// fast atan2 for y >= 0; err ~1e-5 rad
__device__ __forceinline__ float fast_atan2p(float y, float x) {
    float ax = fabsf(x);
    float mn = fminf(ax, y), mx = fmaxf(ax, y);
    float rc = mx > 0.0f ? __builtin_amdgcn_rcpf(mx) : 0.0f;
    float r = mn * rc;
    float t2 = r * r;
    float p = r * (0.99997726f + t2 * (-0.33262347f + t2 * (0.19354346f +
              t2 * (-0.11643287f + t2 * (0.05265332f + t2 * (-0.01172120f))))));
    float a = (y > ax) ? (1.5707963267948966f - p) : p;
    if (x < 0.0f) a = 3.14159265358979f - a;
    return a;
}
__device__ __forceinline__ float angle3(float axv, float ayv, float azv,
                                        float bxv, float byv, float bzv) {
    float cx = ayv * bzv - azv * byv;
    float cy = azv * bxv - axv * bzv;
    float cz = axv * byv - ayv * bxv;
    float cs = cx * cx + cy * cy + cz * cz;
    float cn = cs > 0.0f ? sqrtf(cs) : 0.0f;
    float d  = axv * bxv + ayv * byv + azv * bzv;
    return fast_atan2p(cn, d);   // cn==0&&d==0 -> 0 == atan2(0,1)
}

// ---- setup: hash build (blocks 0..1023) + weight frags + x->bf16 + bounds
__global__ __launch_bounds__(256) void setup_kernel(
    const int* __restrict__ ei, unsigned* __restrict__ hkeys,
    unsigned* __restrict__ hvals,
    const float* __restrict__ W1, const float* __restrict__ b1,
    const float* __restrict__ W2, const float* __restrict__ Wg,
    const float* __restrict__ x, const int* __restrict__ batch,
    int* __restrict__ bounds,
    unsigned short* __restrict__ w1f, unsigned short* __restrict__ w2f,
    unsigned short* __restrict__ wgf, unsigned short* __restrict__ xbf) {
    int gb = blockIdx.x;
    if (gb < E_G / 256) {
        int e = gb * 256 + threadIdx.x;
        unsigned key = (unsigned)(ei[e] * N_PTS + ei[E_G + e]);
        unsigned h = hash_fn(key);
        for (;;) {
            unsigned old = atomicCAS(&hkeys[h], HASH_EMPTY, key);
            if (old == HASH_EMPTY || old == key) {
                atomicMin(&hvals[h], (unsigned)e);   // stable: min edge id wins
                break;
            }
            h = (h + 1u) & HASH_MASK;
        }
        return;
    }
    int t = (gb - E_G / 256) * 256 + threadIdx.x;   // [0, 65536)
    // x -> bf16 (RNE), 8 elems per thread: 65536*8 = 524288 = N_PTS*F_IN
    {
        const float4* xr = (const float4*)x;
        float4 a = xr[t * 2], b = xr[t * 2 + 1];
        union { bf16x8 v; u32 d[4]; } u;
        u.d[0] = pack2bf(a.x, a.y); u.d[1] = pack2bf(a.z, a.w);
        u.d[2] = pack2bf(b.x, b.y); u.d[3] = pack2bf(b.z, b.w);
        *(bf16x8*)(xbf + (size_t)t * 8) = u.v;
    }
    if (t < 12288) {   // A-frags of W1^T: 3 kt * 8 mt * 64 lane * 8 i
        int i = t & 7, lane = (t >> 3) & 63, mt = (t >> 9) & 7, kt = t >> 12;
        int c1 = mt * 16 + (lane & 15);
        int f  = kt * 32 + (lane >> 4) * 8 + i;
        float v = 0.0f;
        if (f < 72) v = W1[f * H_DIM + c1];
        else if (f == 72) v = b1[c1];   // bias-as-feature
        w1f[t] = f2bf(v);
    }
    if (t < 16384) {   // B-frags: 4 kt * 8 nt * 64 lane * 8 i
        int i = t & 7, lane = (t >> 3) & 63, nt = (t >> 9) & 7, kt = t >> 12;
        int c = nt * 16 + (lane & 15);
        int h = kt * 32 + (lane >> 4) * 8 + i;
        w2f[t] = f2bf(W2[h * H_DIM + c]);
        wgf[t] = f2bf(Wg[h * OUT_DIM + c]);
    }
    if (gb == E_G / 256 + 255 && threadIdx.x <= 8) {   // batch segment bounds
        int q = threadIdx.x;
        int a = 0, c = N_PTS;
        while (a < c) { int m = (a + c) >> 1; if (batch[m] < q) a = m + 1; else c = m; }
        bounds[q] = a;
    }
}

// --- fused radius-search + msg + MFMA MLP + max-agg (wave = point, no barriers)
// per-wave 4 KB LDS: [0,256) nbrlist(64 int) | [256,1280) pkrow(64x16B)
//                    | [1280,3840) chunk(32xRSC us)  [phase-A overlay: d2s/js]
__global__ __launch_bounds__(256)
__attribute__((amdgpu_waves_per_eu(2, 4)))
void mlp_kernel(
    const unsigned short* __restrict__ xbf, const float* __restrict__ pos,
    const float* __restrict__ normal, const float* __restrict__ edge_attr,
    const unsigned* __restrict__ hkeys, const unsigned* __restrict__ hvals,
    const int* __restrict__ batch, const int* __restrict__ bounds,
    const unsigned short* __restrict__ w1f, const unsigned short* __restrict__ w2f,
    const float* __restrict__ b2, float* __restrict__ agg) {
    __shared__ __align__(16) unsigned char smem[4][4096];
    int tid = threadIdx.x;
    int l = tid & 63, w = tid >> 6;
    int p = blockIdx.x * 4 + w;
    int lo16 = l & 15, hi4 = l >> 4;
    unsigned char* wbase = smem[w];
    int*   nbrlist = (int*)wbase;
    int*   pkrow   = (int*)(wbase + 256);
    float* d2s     = (float*)(wbase + 1280);
    int*   js      = (int*)(wbase + 2304);
    unsigned short* cb = (unsigned short*)(wbase + 1280);

    // ================= phase A: radius ball query (K=64, r^2=4, per batch) ===
    float pxi = pos[p * 3], pyi = pos[p * 3 + 1], pzi = pos[p * 3 + 2];
    float p2i = pxi * pxi + pyi * pyi + pzi * pzi;
    {
        int b = batch[p];
        int lo = bounds[b], hi = bounds[b + 1];
        int cnt0 = 0;
        for (int j0 = lo; j0 < hi; j0 += 64) {
            int j = j0 + l;
            bool valid = false; float d2 = 0.0f;
            if (j < hi) {
                float xj = pos[j * 3], yj = pos[j * 3 + 1], zj = pos[j * 3 + 2];
                float p2j = xj * xj + yj * yj + zj * zj;
                float dt  = pxi * xj + pyi * yj + pzi * zj;
                d2 = p2i + p2j - 2.0f * dt;   // ref formula; self -> exactly 0
                valid = d2 <= 4.0f;
            }
            unsigned long long mask = __ballot(valid);
            int pp = cnt0 + __popcll(mask & ((1ull << l) - 1ull));
            if (valid && pp < CAND) { d2s[pp] = d2; js[pp] = j; }
            cnt0 += __popcll(mask);
        }
        if (cnt0 > CAND) cnt0 = CAND;
        if (cnt0 <= K_NBR) {
            nbrlist[l] = (l < cnt0) ? js[l] : -1;
        } else {
            // rare: exact top-K by (d2 asc, index asc) == jax top_k tie-break
            for (int idx = l; idx < cnt0; idx += 64) {
                float d2 = d2s[idx]; int jj = js[idx];
                int rank = 0;
                for (int u = 0; u < cnt0; ++u)
                    rank += (d2s[u] < d2) || (d2s[u] == d2 && js[u] < jj);
                if (rank < K_NBR) nbrlist[rank] = jj;
            }
            cnt0 = K_NBR;
        }
        int cnt = cnt0;

    // ================= phase B: ppf + edge_attr for own slot =================
    int jme = nbrlist[l];
    int jc = max(jme, 0);
    float nxi = normal[p * 3], nyi = normal[p * 3 + 1], nzi = normal[p * 3 + 2];
    float pxj = pos[jc * 3], pyj = pos[jc * 3 + 1], pzj = pos[jc * 3 + 2];
    float nxj = normal[jc * 3], nyj = normal[jc * 3 + 1], nzj = normal[jc * 3 + 2];
    float vx = pxj - pxi, vy = pyj - pyi, vz = pzj - pzi;
    float sq = vx * vx + vy * vy + vz * vz;
    float dd = sq > 0.0f ? sqrtf(sq) : 0.0f;
    float a1 = angle3(nxi, nyi, nzi, vx, vy, vz);
    float a2 = angle3(nxj, nyj, nzj, vx, vy, vz);
    float a3 = angle3(nxi, nyi, nzi, nxj, nyj, nzj);
    unsigned key = (unsigned)(jc * N_PTS + p);
    unsigned hh = hash_fn(key);
    unsigned eidx = E_G;   // sentinel row
    for (;;) {
        unsigned k2 = hkeys[hh];
        if (k2 == key) { eidx = hvals[hh]; break; }
        if (k2 == HASH_EMPTY) break;
        hh = (hh + 1u) & HASH_MASK;
    }
    float4 er = *(const float4*)(edge_attr + (size_t)eidx * D_E);
    int4 pk;
    pk.x = (int)pack2bf(dd, a1);   pk.y = (int)pack2bf(a2, a3);
    pk.z = (int)pack2bf(er.x, er.y); pk.w = (int)pack2bf(er.z, er.w);
    ((int4*)pkrow)[l] = pk;

    // ===== layer 1: D1[c1][slot] = W1^T @ msg^T; LDS-chunk reshuffle to haf ==
    bf16x8 haf[4][4];   // [ms][kt]
    #pragma unroll
    for (int pass = 0; pass < 2; ++pass) {
        bf16x8 xf[2][2];    // [nsl][kt]
        bf16x8 ktf[2];
        #pragma unroll
        for (int nsl = 0; nsl < 2; ++nsl) {
            int slot = (pass * 2 + nsl) * 16 + lo16;
            int j = nbrlist[slot];
            const unsigned short* xb = xbf + (size_t)max(j, 0) * F_IN;
            #pragma unroll
            for (int kt = 0; kt < 2; ++kt)
                xf[nsl][kt] = *(const bf16x8*)(xb + kt * 32 + hi4 * 8);
            // kt=2 B-frag: f64..71 = ppf+eattr (hi4==0); f72 bias=1 (hi4==1)
            int4 q = ((const int4*)pkrow)[slot];
            union { bf16x8 v; u32 d[4]; } u;
            u.d[0] = hi4 == 0 ? (u32)q.x : (hi4 == 1 ? 0x3F80u : 0u);
            u.d[1] = hi4 == 0 ? (u32)q.y : 0u;
            u.d[2] = hi4 == 0 ? (u32)q.z : 0u;
            u.d[3] = hi4 == 0 ? (u32)q.w : 0u;
            ktf[nsl] = u.v;
        }
        #pragma unroll
        for (int mtp = 0; mtp < 4; ++mtp) {
            #pragma unroll
            for (int sub = 0; sub < 2; ++sub) {
                int mt = mtp * 2 + sub;
                bf16x8 af0 = *(const bf16x8*)(w1f + ((0 * 8 + mt) * 64 + l) * 8);
                bf16x8 af1 = *(const bf16x8*)(w1f + ((1 * 8 + mt) * 64 + l) * 8);
                bf16x8 af2 = *(const bf16x8*)(w1f + ((2 * 8 + mt) * 64 + l) * 8);
                #pragma unroll
                for (int nsl = 0; nsl < 2; ++nsl) {
                    f32x4 acc = (f32x4)0.0f;
                    acc = __builtin_amdgcn_mfma_f32_16x16x32_bf16(af0, xf[nsl][0], acc, 0, 0, 0);
                    acc = __builtin_amdgcn_mfma_f32_16x16x32_bf16(af1, xf[nsl][1], acc, 0, 0, 0);
                    acc = __builtin_amdgcn_mfma_f32_16x16x32_bf16(af2, ktf[nsl], acc, 0, 0, 0);
                    // relu + 2x v_perm pack; lane holds c1=mt*16+hi4*4+r, slot-col lo16
                    uint2 o;
                    o.x = pack2t(fmaxf(acc[0], 0.0f), fmaxf(acc[1], 0.0f));
                    o.y = pack2t(fmaxf(acc[2], 0.0f), fmaxf(acc[3], 0.0f));
                    *(uint2*)(cb + (nsl * 16 + lo16) * RSC + sub * 16 + hi4 * 4) = o;
                }
            }
            // read back as layer-2 A-frags: row=slot(lane&15), k=c1(hi4*8+i)
            #pragma unroll
            for (int nsl = 0; nsl < 2; ++nsl)
                haf[pass * 2 + nsl][mtp] =
                    *(const bf16x8*)(cb + (nsl * 16 + lo16) * RSC + hi4 * 8);
        }
    }

    // ===== layer 2: D2[slot][c2] = h1 @ W2 (+b2); masked relu-max over slots =
    #pragma unroll
    for (int nt = 0; nt < 8; ++nt) {
        float bb = b2[nt * 16 + lo16];
        f32x4 acc[4];
        #pragma unroll
        for (int ms = 0; ms < 4; ++ms) { f32x4 bv = {bb, bb, bb, bb}; acc[ms] = bv; }
        #pragma unroll
        for (int kt = 0; kt < 4; ++kt) {
            bf16x8 bfr = *(const bf16x8*)(w2f + ((kt * 8 + nt) * 64 + l) * 8);
            #pragma unroll
            for (int ms = 0; ms < 4; ++ms)
                acc[ms] = __builtin_amdgcn_mfma_f32_16x16x32_bf16(haf[ms][kt], bfr, acc[ms], 0, 0, 0);
        }
        // m starts at 0: max over valid of relu(h) == max(0, max over valid h)
        float m = 0.0f;
        #pragma unroll
        for (int ms = 0; ms < 4; ++ms)
            #pragma unroll
            for (int r = 0; r < 4; ++r) {
                int slot = ms * 16 + hi4 * 4 + r;
                m = fmaxf(m, slot < cnt ? acc[ms][r] : 0.0f);
            }
        m = fmaxf(m, __shfl_xor(m, 16, 64));
        m = fmaxf(m, __shfl_xor(m, 32, 64));
        if (l < 16) agg[(size_t)p * H_DIM + nt * 16 + l] = m;
    }
    }   // scope of cnt
}

// ------------------- global_nn (MFMA): out = agg @ Wg + bg   (+tail blocks)
__global__ __launch_bounds__(256) void final_kernel(
    const float* __restrict__ agg, const unsigned short* __restrict__ wgf,
    const float* __restrict__ bg, const float* __restrict__ pos,
    const int* __restrict__ batch, float* __restrict__ out) {
    if (blockIdx.x >= N_PTS / 64) {   // tail: pos + batch passthrough
        int idx = (blockIdx.x - N_PTS / 64) * 256 + threadIdx.x;
        if (idx < N_PTS * 3) out[N_PTS * OUT_DIM + idx] = pos[idx];
        if (idx < N_PTS)     out[N_PTS * OUT_DIM + N_PTS * 3 + idx] = (float)batch[idx];
        return;
    }
    int tid = threadIdx.x, l = tid & 63, w = tid >> 6;
    int pbase = blockIdx.x * 64 + w * 16;
    int lo16 = l & 15, hi4 = l >> 4;
    f32x4 acc[8];
    #pragma unroll
    for (int nt = 0; nt < 8; ++nt) {
        float bb = bg[nt * 16 + lo16];
        f32x4 bv = {bb, bb, bb, bb}; acc[nt] = bv;
    }
    #pragma unroll
    for (int kt = 0; kt < 4; ++kt) {
        const float* ab = agg + (size_t)(pbase + lo16) * H_DIM + kt * 32 + hi4 * 8;
        float4 a = *(const float4*)ab, b = *(const float4*)(ab + 4);
        union { bf16x8 v; u32 d[4]; } u;
        u.d[0] = pack2t(a.x, a.y); u.d[1] = pack2t(a.z, a.w);
        u.d[2] = pack2t(b.x, b.y); u.d[3] = pack2t(b.z, b.w);
        bf16x8 afr = u.v;
        #pragma unroll
        for (int nt = 0; nt < 8; ++nt) {
            bf16x8 bfr = *(const bf16x8*)(wgf + ((kt * 8 + nt) * 64 + l) * 8);
            acc[nt] = __builtin_amdgcn_mfma_f32_16x16x32_bf16(afr, bfr, acc[nt], 0, 0, 0);
        }
    }
    #pragma unroll
    for (int nt = 0; nt < 8; ++nt)
        #pragma unroll
        for (int r = 0; r < 4; ++r)
            out[(size_t)(pbase + hi4 * 4 + r) * OUT_DIM + nt * 16 + lo16] = acc[nt][r];
}

// ---------------------------------------------------------------------------
extern "C" void kernel_launch(void* const* d_in, const int* in_sizes, int n_in,
                              void* d_out, int out_size, void* d_ws, size_t ws_size,
                              hipStream_t stream) {
    const float* x         = (const float*)d_in[0];
    const float* pos       = (const float*)d_in[1];
    const float* normal    = (const float*)d_in[2];
    const int*   batch     = (const int*)d_in[3];
    const float* edge_attr = (const float*)d_in[4];
    const int*   edge_index= (const int*)d_in[5];
    const float* W1        = (const float*)d_in[6];
    const float* b1        = (const float*)d_in[7];
    const float* W2        = (const float*)d_in[8];
    const float* b2        = (const float*)d_in[9];
    const float* Wg        = (const float*)d_in[10];
    const float* bg        = (const float*)d_in[11];
    float* out = (float*)d_out;

    unsigned char* wsb = (unsigned char*)d_ws;
    unsigned* hkeys = (unsigned*)wsb;                                   // 2 MB
    unsigned* hvals = (unsigned*)(wsb + (size_t)HASH_SIZE * 4);         // 2 MB
    unsigned short* w1f = (unsigned short*)(wsb + (size_t)HASH_SIZE * 8);
    unsigned short* w2f = w1f + 12288;
    unsigned short* wgf = w2f + 16384;
    unsigned short* xbf = wgf + 16384;                                  // 1 MB
    float* agg = (float*)(xbf + (size_t)N_PTS * F_IN);                  // 4 MB
    int* bounds = (int*)((unsigned char*)agg + (size_t)N_PTS * H_DIM * 4);

    hipMemsetAsync(hkeys, 0xFF, (size_t)HASH_SIZE * 8, stream);

    setup_kernel<<<E_G / 256 + 256, 256, 0, stream>>>(
        edge_index, hkeys, hvals, W1, b1, W2, Wg, x, batch, bounds,
        w1f, w2f, wgf, xbf);
    mlp_kernel<<<N_PTS / 4, 256, 0, stream>>>(xbf, pos, normal, edge_attr,
                                              hkeys, hvals, batch, bounds,
                                              w1f, w2f, b2, agg);
    final_kernel<<<N_PTS / 64 + N_PTS / 64, 256, 0, stream>>>(agg, wgf, bg, pos, batch, out);
}

// Round 8
// 112.872 us; speedup vs baseline: 8.3743x; 1.0072x over previous
//
#include <hip/hip_runtime.h>
#include <math.h>

#define N_PTS   8192
#define F_IN    64
#define D_E     4
#define H_DIM   128
#define OUT_DIM 128
#define K_NBR   64
#define E_G     262144
#define HASH_BITS 19
#define HASH_SIZE (1u << HASH_BITS)
#define HASH_MASK (HASH_SIZE - 1u)
#define HASH_EMPTY 0xFFFFFFFFu
#define CAND 256
#define RSC 40    // chunk row stride in ushorts (80 B)
#define ARS 136   // aggbf row stride in ushorts (272 B, 16B-aligned)

typedef __attribute__((ext_vector_type(8))) short bf16x8;
typedef __attribute__((ext_vector_type(4))) float f32x4;
typedef unsigned int u32;

__device__ __forceinline__ unsigned hash_fn(unsigned key) {
    return (key * 2654435761u) >> (32 - HASH_BITS);
}
__device__ __forceinline__ unsigned short f2bf(float f) {   // RNE f32->bf16
    union { float f; unsigned u; } v; v.f = f;
    unsigned r = v.u + 0x7FFFu + ((v.u >> 16) & 1u);
    return (unsigned short)(r >> 16);
}
__device__ __forceinline__ u32 pack2bf(float a, float b) {  // RNE pair
    return (u32)f2bf(a) | ((u32)f2bf(b) << 16);
}
// truncation pack: D = {hi16(b), hi16(a)} in ONE v_perm_b32
__device__ __forceinline__ u32 pack2t(float a, float b) {
    return __builtin_amdgcn_perm(__float_as_uint(b), __float_as_uint(a), 0x07060302u);
}

// fast atan2 for y >= 0; err ~1e-5 rad
__device__ __forceinline__ float fast_atan2p(float y, float x) {
    float ax = fabsf(x);
    float mn = fminf(ax, y), mx = fmaxf(ax, y);
    float rc = mx > 0.0f ? __builtin_amdgcn_rcpf(mx) : 0.0f;
    float r = mn * rc;
    float t2 = r * r;
    float p = r * (0.99997726f + t2 * (-0.33262347f + t2 * (0.19354346f +
              t2 * (-0.11643287f + t2 * (0.05265332f + t2 * (-0.01172120f))))));
    float a = (y > ax) ? (1.5707963267948966f - p) : p;
    if (x < 0.0f) a = 3.14159265358979f - a;
    return a;
}
__device__ __forceinline__ float angle3(float axv, float ayv, float azv,
                                        float bxv, float byv, float bzv) {
    float cx = ayv * bzv - azv * byv;
    float cy = azv * bxv - axv * bzv;
    float cz = axv * byv - ayv * bxv;
    float cs = cx * cx + cy * cy + cz * cz;
    float cn = cs > 0.0f ? sqrtf(cs) : 0.0f;
    float d  = axv * bxv + ayv * byv + azv * bzv;
    return fast_atan2p(cn, d);   // cn==0&&d==0 -> 0 == atan2(0,1)
}

// ---- setup: hash build | weight frags + x->bf16 + bounds | out tail copy
__global__ __launch_bounds__(256) void setup_kernel(
    const int* __restrict__ ei, unsigned* __restrict__ hkeys,
    unsigned* __restrict__ hvals,
    const float* __restrict__ W1, const float* __restrict__ b1,
    const float* __restrict__ W2, const float* __restrict__ Wg,
    const float* __restrict__ x, const float* __restrict__ pos,
    const int* __restrict__ batch, int* __restrict__ bounds,
    unsigned short* __restrict__ w1f, unsigned short* __restrict__ w2f,
    unsigned short* __restrict__ wgf, unsigned short* __restrict__ xbf,
    float* __restrict__ out) {
    int gb = blockIdx.x;
    if (gb < E_G / 256) {                       // ---- hash build
        int e = gb * 256 + threadIdx.x;
        unsigned key = (unsigned)(ei[e] * N_PTS + ei[E_G + e]);
        unsigned h = hash_fn(key);
        for (;;) {
            unsigned old = atomicCAS(&hkeys[h], HASH_EMPTY, key);
            if (old == HASH_EMPTY || old == key) {
                atomicMin(&hvals[h], (unsigned)e);   // stable: min edge id wins
                break;
            }
            h = (h + 1u) & HASH_MASK;
        }
        return;
    }
    if (gb >= E_G / 256 + 256) {                // ---- tail: pos + batch copy
        int idx = (gb - (E_G / 256 + 256)) * 256 + threadIdx.x;
        if (idx < N_PTS * 3) out[N_PTS * OUT_DIM + idx] = pos[idx];
        else out[N_PTS * OUT_DIM + idx] = (float)batch[idx - N_PTS * 3];
        return;
    }
    int t = (gb - E_G / 256) * 256 + threadIdx.x;   // [0, 65536)
    {   // x -> bf16 (RNE), 8 elems/thread: 65536*8 = N_PTS*F_IN
        const float4* xr = (const float4*)x;
        float4 a = xr[t * 2], b = xr[t * 2 + 1];
        union { bf16x8 v; u32 d[4]; } u;
        u.d[0] = pack2bf(a.x, a.y); u.d[1] = pack2bf(a.z, a.w);
        u.d[2] = pack2bf(b.x, b.y); u.d[3] = pack2bf(b.z, b.w);
        *(bf16x8*)(xbf + (size_t)t * 8) = u.v;
    }
    if (t < 12288) {   // A-frags of W1^T: 3 kt * 8 mt * 64 lane * 8 i
        int i = t & 7, lane = (t >> 3) & 63, mt = (t >> 9) & 7, kt = t >> 12;
        int c1 = mt * 16 + (lane & 15);
        int f  = kt * 32 + (lane >> 4) * 8 + i;
        float v = 0.0f;
        if (f < 72) v = W1[f * H_DIM + c1];
        else if (f == 72) v = b1[c1];   // bias-as-feature
        w1f[t] = f2bf(v);
    }
    if (t < 16384) {   // B-frags: 4 kt * 8 nt * 64 lane * 8 i
        int i = t & 7, lane = (t >> 3) & 63, nt = (t >> 9) & 7, kt = t >> 12;
        int c = nt * 16 + (lane & 15);
        int h = kt * 32 + (lane >> 4) * 8 + i;
        w2f[t] = f2bf(W2[h * H_DIM + c]);
        wgf[t] = f2bf(Wg[h * OUT_DIM + c]);
    }
    if (gb == E_G / 256 + 255 && threadIdx.x <= 8) {   // batch bounds
        int q = threadIdx.x;
        int a = 0, c = N_PTS;
        while (a < c) { int m = (a + c) >> 1; if (batch[m] < q) a = m + 1; else c = m; }
        bounds[q] = a;
    }
}

// --- fused radius-search + msg + MFMA MLP + max-agg + final GEMV (wave=point)
// per-wave 4 KB LDS: [0,256) nbrlist | [256,1280) pkrow | [1280,3840) chunk
//                    (phase-A overlay: d2s/js)   + block-shared aggbf[4][ARS]
__global__ __launch_bounds__(256)
__attribute__((amdgpu_waves_per_eu(2, 4)))
void mlp_kernel(
    const unsigned short* __restrict__ xbf, const float* __restrict__ pos,
    const float* __restrict__ normal, const float* __restrict__ edge_attr,
    const unsigned* __restrict__ hkeys, const unsigned* __restrict__ hvals,
    const int* __restrict__ batch, const int* __restrict__ bounds,
    const unsigned short* __restrict__ w1f, const unsigned short* __restrict__ w2f,
    const unsigned short* __restrict__ wgf,
    const float* __restrict__ b2, const float* __restrict__ bg,
    float* __restrict__ out) {
    __shared__ __align__(16) unsigned char smem[4][4096];
    __shared__ __align__(16) unsigned short aggbf[4 * ARS];
    int tid = threadIdx.x;
    int l = tid & 63, w = tid >> 6;
    int p = blockIdx.x * 4 + w;
    int lo16 = l & 15, hi4 = l >> 4;
    unsigned char* wbase = smem[w];
    int*   nbrlist = (int*)wbase;
    int*   pkrow   = (int*)(wbase + 256);
    float* d2s     = (float*)(wbase + 1280);
    int*   js      = (int*)(wbase + 2304);
    unsigned short* cb = (unsigned short*)(wbase + 1280);

    // ========== phase A: radius ball query, stripe-per-lane + prefix scan ====
    float pxi = pos[p * 3], pyi = pos[p * 3 + 1], pzi = pos[p * 3 + 2];
    float p2i = pxi * pxi + pyi * pyi + pzi * pzi;
    int cnt;
    {
        int b = batch[p];
        int lo = bounds[b], hi = bounds[b + 1];
        int len = hi - lo;
        int per = (len + 63) >> 6;
        int jb = lo + l * per;
        int je = min(jb + per, hi);
        // pass 1: count my stripe (ILP-friendly, no cross-lane ops)
        int myc = 0;
        for (int j = jb; j < je; ++j) {
            float xj = pos[j * 3], yj = pos[j * 3 + 1], zj = pos[j * 3 + 2];
            float p2j = xj * xj + yj * yj + zj * zj;
            float d2 = p2i + p2j - 2.0f * (pxi * xj + pyi * yj + pzi * zj);
            myc += (d2 <= 4.0f) ? 1 : 0;
        }
        // exclusive prefix sum across the wave
        int inc = myc;
        #pragma unroll
        for (int s = 1; s < 64; s <<= 1) {
            int v = __shfl_up(inc, s, 64);
            if (l >= s) inc += v;
        }
        int total = __shfl(inc, 63, 64);
        int off = inc - myc;
        // pass 2: recompute + store at offset (order = ascending j)
        for (int j = jb; j < je; ++j) {
            float xj = pos[j * 3], yj = pos[j * 3 + 1], zj = pos[j * 3 + 2];
            float p2j = xj * xj + yj * yj + zj * zj;
            float d2 = p2i + p2j - 2.0f * (pxi * xj + pyi * yj + pzi * zj);
            if (d2 <= 4.0f) {
                if (off < CAND) { d2s[off] = d2; js[off] = j; }
                ++off;
            }
        }
        cnt = min(total, CAND);
        if (cnt <= K_NBR) {
            nbrlist[l] = (l < cnt) ? js[l] : -1;
        } else {
            // rare: exact top-K by (d2 asc, index asc) == jax top_k tie-break
            for (int idx = l; idx < cnt; idx += 64) {
                float d2 = d2s[idx]; int jj = js[idx];
                int rank = 0;
                for (int u = 0; u < cnt; ++u)
                    rank += (d2s[u] < d2) || (d2s[u] == d2 && js[u] < jj);
                if (rank < K_NBR) nbrlist[rank] = jj;
            }
            cnt = K_NBR;
        }
    }

    // ========== phase B: ppf + edge_attr for own slot ========================
    int jme = nbrlist[l];
    int jc = max(jme, 0);
    float nxi = normal[p * 3], nyi = normal[p * 3 + 1], nzi = normal[p * 3 + 2];
    float pxj = pos[jc * 3], pyj = pos[jc * 3 + 1], pzj = pos[jc * 3 + 2];
    float nxj = normal[jc * 3], nyj = normal[jc * 3 + 1], nzj = normal[jc * 3 + 2];
    float vx = pxj - pxi, vy = pyj - pyi, vz = pzj - pzi;
    float sq = vx * vx + vy * vy + vz * vz;
    float dd = sq > 0.0f ? sqrtf(sq) : 0.0f;
    float a1 = angle3(nxi, nyi, nzi, vx, vy, vz);
    float a2 = angle3(nxj, nyj, nzj, vx, vy, vz);
    float a3 = angle3(nxi, nyi, nzi, nxj, nyj, nzj);
    unsigned key = (unsigned)(jc * N_PTS + p);
    unsigned hh = hash_fn(key);
    unsigned eidx = E_G;   // sentinel row
    for (;;) {
        unsigned k2 = hkeys[hh];
        if (k2 == key) { eidx = hvals[hh]; break; }
        if (k2 == HASH_EMPTY) break;
        hh = (hh + 1u) & HASH_MASK;
    }
    float4 er = *(const float4*)(edge_attr + (size_t)eidx * D_E);
    int4 pk;
    pk.x = (int)pack2bf(dd, a1);   pk.y = (int)pack2bf(a2, a3);
    pk.z = (int)pack2bf(er.x, er.y); pk.w = (int)pack2bf(er.z, er.w);
    ((int4*)pkrow)[l] = pk;

    // ===== layer 1: D1[c1][slot] = W1^T @ msg^T; LDS-chunk reshuffle to haf ==
    bf16x8 haf[4][4];   // [ms][kt]
    #pragma unroll
    for (int pass = 0; pass < 2; ++pass) {
        bf16x8 xf[2][2];    // [nsl][kt]
        bf16x8 ktf[2];
        #pragma unroll
        for (int nsl = 0; nsl < 2; ++nsl) {
            int slot = (pass * 2 + nsl) * 16 + lo16;
            int j = nbrlist[slot];
            const unsigned short* xb = xbf + (size_t)max(j, 0) * F_IN;
            #pragma unroll
            for (int kt = 0; kt < 2; ++kt)
                xf[nsl][kt] = *(const bf16x8*)(xb + kt * 32 + hi4 * 8);
            // kt=2 B-frag: f64..71 = ppf+eattr (hi4==0); f72 bias=1 (hi4==1)
            int4 q = ((const int4*)pkrow)[slot];
            union { bf16x8 v; u32 d[4]; } u;
            u.d[0] = hi4 == 0 ? (u32)q.x : (hi4 == 1 ? 0x3F80u : 0u);
            u.d[1] = hi4 == 0 ? (u32)q.y : 0u;
            u.d[2] = hi4 == 0 ? (u32)q.z : 0u;
            u.d[3] = hi4 == 0 ? (u32)q.w : 0u;
            ktf[nsl] = u.v;
        }
        #pragma unroll
        for (int mtp = 0; mtp < 4; ++mtp) {
            #pragma unroll
            for (int sub = 0; sub < 2; ++sub) {
                int mt = mtp * 2 + sub;
                bf16x8 af0 = *(const bf16x8*)(w1f + ((0 * 8 + mt) * 64 + l) * 8);
                bf16x8 af1 = *(const bf16x8*)(w1f + ((1 * 8 + mt) * 64 + l) * 8);
                bf16x8 af2 = *(const bf16x8*)(w1f + ((2 * 8 + mt) * 64 + l) * 8);
                #pragma unroll
                for (int nsl = 0; nsl < 2; ++nsl) {
                    f32x4 acc = (f32x4)0.0f;
                    acc = __builtin_amdgcn_mfma_f32_16x16x32_bf16(af0, xf[nsl][0], acc, 0, 0, 0);
                    acc = __builtin_amdgcn_mfma_f32_16x16x32_bf16(af1, xf[nsl][1], acc, 0, 0, 0);
                    acc = __builtin_amdgcn_mfma_f32_16x16x32_bf16(af2, ktf[nsl], acc, 0, 0, 0);
                    uint2 o;
                    o.x = pack2t(fmaxf(acc[0], 0.0f), fmaxf(acc[1], 0.0f));
                    o.y = pack2t(fmaxf(acc[2], 0.0f), fmaxf(acc[3], 0.0f));
                    *(uint2*)(cb + (nsl * 16 + lo16) * RSC + sub * 16 + hi4 * 4) = o;
                }
            }
            #pragma unroll
            for (int nsl = 0; nsl < 2; ++nsl)
                haf[pass * 2 + nsl][mtp] =
                    *(const bf16x8*)(cb + (nsl * 16 + lo16) * RSC + hi4 * 8);
        }
    }

    // ===== layer 2: D2[slot][c2] = h1 @ W2 (+b2); masked relu-max over slots =
    #pragma unroll
    for (int nt = 0; nt < 8; ++nt) {
        float bb = b2[nt * 16 + lo16];
        f32x4 acc[4];
        #pragma unroll
        for (int ms = 0; ms < 4; ++ms) { f32x4 bv = {bb, bb, bb, bb}; acc[ms] = bv; }
        #pragma unroll
        for (int kt = 0; kt < 4; ++kt) {
            bf16x8 bfr = *(const bf16x8*)(w2f + ((kt * 8 + nt) * 64 + l) * 8);
            #pragma unroll
            for (int ms = 0; ms < 4; ++ms)
                acc[ms] = __builtin_amdgcn_mfma_f32_16x16x32_bf16(haf[ms][kt], bfr, acc[ms], 0, 0, 0);
        }
        // m starts at 0: max over valid of relu == max(0, max over valid)
        float m = 0.0f;
        #pragma unroll
        for (int ms = 0; ms < 4; ++ms)
            #pragma unroll
            for (int r = 0; r < 4; ++r) {
                int slot = ms * 16 + hi4 * 4 + r;
                m = fmaxf(m, slot < cnt ? acc[ms][r] : 0.0f);
            }
        m = fmaxf(m, __shfl_xor(m, 16, 64));
        m = fmaxf(m, __shfl_xor(m, 32, 64));
        // stash agg row (bf16 trunc) into block-shared aggbf[w][c]
        if ((nt >> 1) == hi4)
            aggbf[w * ARS + nt * 16 + lo16] =
                (unsigned short)(__float_as_uint(m) >> 16);
    }

    // ===== fused global_nn: out[4 pts][128] = agg @ Wg + bg ==================
    __syncthreads();
    // A-frag rows = block's 4 points (rows 4..15 mirror rows 0..3, discarded)
    int arow = lo16 & 3;
    bf16x8 afr2[4];
    #pragma unroll
    for (int kt = 0; kt < 4; ++kt)
        afr2[kt] = *(const bf16x8*)(aggbf + arow * ARS + kt * 32 + hi4 * 8);
    int ntA = w * 2, ntB = w * 2 + 1;
    f32x4 accA = (f32x4)0.0f, accB = (f32x4)0.0f;
    #pragma unroll
    for (int kt = 0; kt < 4; ++kt) {
        bf16x8 bfrA = *(const bf16x8*)(wgf + ((kt * 8 + ntA) * 64 + l) * 8);
        bf16x8 bfrB = *(const bf16x8*)(wgf + ((kt * 8 + ntB) * 64 + l) * 8);
        accA = __builtin_amdgcn_mfma_f32_16x16x32_bf16(afr2[kt], bfrA, accA, 0, 0, 0);
        accB = __builtin_amdgcn_mfma_f32_16x16x32_bf16(afr2[kt], bfrB, accB, 0, 0, 0);
    }
    if (hi4 == 0) {   // C rows 0..3 = points 0..3
        int cA = ntA * 16 + lo16, cB = ntB * 16 + lo16;
        float bgA = bg[cA], bgB = bg[cB];
        size_t obase = (size_t)(blockIdx.x * 4) * OUT_DIM;
        #pragma unroll
        for (int r = 0; r < 4; ++r) {
            out[obase + (size_t)r * OUT_DIM + cA] = accA[r] + bgA;
            out[obase + (size_t)r * OUT_DIM + cB] = accB[r] + bgB;
        }
    }
}

// ---------------------------------------------------------------------------
extern "C" void kernel_launch(void* const* d_in, const int* in_sizes, int n_in,
                              void* d_out, int out_size, void* d_ws, size_t ws_size,
                              hipStream_t stream) {
    const float* x         = (const float*)d_in[0];
    const float* pos       = (const float*)d_in[1];
    const float* normal    = (const float*)d_in[2];
    const int*   batch     = (const int*)d_in[3];
    const float* edge_attr = (const float*)d_in[4];
    const int*   edge_index= (const int*)d_in[5];
    const float* W1        = (const float*)d_in[6];
    const float* b1        = (const float*)d_in[7];
    const float* W2        = (const float*)d_in[8];
    const float* b2        = (const float*)d_in[9];
    const float* Wg        = (const float*)d_in[10];
    const float* bg        = (const float*)d_in[11];
    float* out = (float*)d_out;

    unsigned char* wsb = (unsigned char*)d_ws;
    unsigned* hkeys = (unsigned*)wsb;                                   // 2 MB
    unsigned* hvals = (unsigned*)(wsb + (size_t)HASH_SIZE * 4);         // 2 MB
    unsigned short* w1f = (unsigned short*)(wsb + (size_t)HASH_SIZE * 8);
    unsigned short* w2f = w1f + 12288;
    unsigned short* wgf = w2f + 16384;
    unsigned short* xbf = wgf + 16384;                                  // 1 MB
    int* bounds = (int*)(xbf + (size_t)N_PTS * F_IN);

    hipMemsetAsync(hkeys, 0xFF, (size_t)HASH_SIZE * 8, stream);

    setup_kernel<<<E_G / 256 + 256 + 128, 256, 0, stream>>>(
        edge_index, hkeys, hvals, W1, b1, W2, Wg, x, pos, batch, bounds,
        w1f, w2f, wgf, xbf, out);
    mlp_kernel<<<N_PTS / 4, 256, 0, stream>>>(xbf, pos, normal, edge_attr,
                                              hkeys, hvals, batch, bounds,
                                              w1f, w2f, wgf, b2, bg, out);
}

// Round 10
// 100.486 us; speedup vs baseline: 9.4066x; 1.1233x over previous
//
#include <hip/hip_runtime.h>
#include <math.h>

#define N_PTS   8192
#define F_IN    64
#define D_E     4
#define H_DIM   128
#define OUT_DIM 128
#define K_NBR   64
#define E_G     262144
#define HASH_BITS 19
#define HASH_SIZE (1u << HASH_BITS)
#define HASH_MASK (HASH_SIZE - 1u)
#define EMPTY64 0xFFFFFFFFFFFFFFFFull
#define CAND 256
#define RSC 40    // chunk row stride in ushorts (80 B)
#define ARS 136   // aggbf row stride in ushorts (272 B)

typedef __attribute__((ext_vector_type(8))) short bf16x8;
typedef __attribute__((ext_vector_type(4))) float f32x4;
typedef unsigned int u32;
typedef unsigned long long u64;

__device__ __forceinline__ unsigned hash_fn(unsigned key) {
    return (key * 2654435761u) >> (32 - HASH_BITS);
}
__device__ __forceinline__ unsigned short f2bf(float f) {   // RNE f32->bf16
    union { float f; unsigned u; } v; v.f = f;
    unsigned r = v.u + 0x7FFFu + ((v.u >> 16) & 1u);
    return (unsigned short)(r >> 16);
}
__device__ __forceinline__ u32 pack2bf(float a, float b) {  // RNE pair
    return (u32)f2bf(a) | ((u32)f2bf(b) << 16);
}
// truncation pack: D = {hi16(b), hi16(a)} in ONE v_perm_b32
__device__ __forceinline__ u32 pack2t(float a, float b) {
    return __builtin_amdgcn_perm(__float_as_uint(b), __float_as_uint(a), 0x07060302u);
}

// fast atan2 for y >= 0; err ~1e-5 rad
__device__ __forceinline__ float fast_atan2p(float y, float x) {
    float ax = fabsf(x);
    float mn = fminf(ax, y), mx = fmaxf(ax, y);
    float rc = mx > 0.0f ? __builtin_amdgcn_rcpf(mx) : 0.0f;
    float r = mn * rc;
    float t2 = r * r;
    float p = r * (0.99997726f + t2 * (-0.33262347f + t2 * (0.19354346f +
              t2 * (-0.11643287f + t2 * (0.05265332f + t2 * (-0.01172120f))))));
    float a = (y > ax) ? (1.5707963267948966f - p) : p;
    if (x < 0.0f) a = 3.14159265358979f - a;
    return a;
}
__device__ __forceinline__ float angle3(float axv, float ayv, float azv,
                                        float bxv, float byv, float bzv) {
    float cx = ayv * bzv - azv * byv;
    float cy = azv * bxv - axv * bzv;
    float cz = axv * byv - ayv * bxv;
    float cs = cx * cx + cy * cy + cz * cz;
    float cn = cs > 0.0f ? sqrtf(cs) : 0.0f;
    float d  = axv * bxv + ayv * byv + azv * bzv;
    return fast_atan2p(cn, d);   // cn==0&&d==0 -> 0 == atan2(0,1)
}

// ---- setup: hash build (64-bit single-CAS) | frags + xbf + bounds | tail ---
__global__ __launch_bounds__(256) void setup_kernel(
    const int* __restrict__ ei, u64* __restrict__ htab,
    const float* __restrict__ W1, const float* __restrict__ b1,
    const float* __restrict__ W2, const float* __restrict__ Wg,
    const float* __restrict__ x, const float* __restrict__ pos,
    const int* __restrict__ batch, int* __restrict__ bounds,
    unsigned short* __restrict__ w1f, unsigned short* __restrict__ w2f,
    unsigned short* __restrict__ wgf, unsigned short* __restrict__ xbf,
    float* __restrict__ out) {
    int gb = blockIdx.x;
    if (gb < E_G / 256) {                       // ---- hash build
        int e = gb * 256 + threadIdx.x;
        unsigned key = (unsigned)(ei[e] * N_PTS + ei[E_G + e]);
        u64 ins = ((u64)key << 32) | (unsigned)e;
        unsigned h = hash_fn(key);
        for (;;) {
            u64 old = atomicCAS(&htab[h], EMPTY64, ins);
            if (old == EMPTY64) break;                    // claimed
            if ((unsigned)(old >> 32) == key) {           // dup key: keep min e
                u64 cur = old;
                while ((unsigned)cur > (unsigned)e) {
                    u64 prev = atomicCAS(&htab[h], cur, ins);
                    if (prev == cur) break;
                    cur = prev;
                }
                break;
            }
            h = (h + 1u) & HASH_MASK;
        }
        return;
    }
    if (gb >= E_G / 256 + 256) {                // ---- tail: pos + batch copy
        int idx = (gb - (E_G / 256 + 256)) * 256 + threadIdx.x;
        if (idx < N_PTS * 3) out[N_PTS * OUT_DIM + idx] = pos[idx];
        else out[N_PTS * OUT_DIM + idx] = (float)batch[idx - N_PTS * 3];
        return;
    }
    int t = (gb - E_G / 256) * 256 + threadIdx.x;   // [0, 65536)
    {   // x -> bf16 (RNE), 8 elems/thread: 65536*8 = N_PTS*F_IN
        const float4* xr = (const float4*)x;
        float4 a = xr[t * 2], b = xr[t * 2 + 1];
        union { bf16x8 v; u32 d[4]; } u;
        u.d[0] = pack2bf(a.x, a.y); u.d[1] = pack2bf(a.z, a.w);
        u.d[2] = pack2bf(b.x, b.y); u.d[3] = pack2bf(b.z, b.w);
        *(bf16x8*)(xbf + (size_t)t * 8) = u.v;
    }
    if (t < 12288) {   // A-frags of W1^T: 3 kt * 8 mt * 64 lane * 8 i
        int i = t & 7, lane = (t >> 3) & 63, mt = (t >> 9) & 7, kt = t >> 12;
        int c1 = mt * 16 + (lane & 15);
        int f  = kt * 32 + (lane >> 4) * 8 + i;
        float v = 0.0f;
        if (f < 72) v = W1[f * H_DIM + c1];
        else if (f == 72) v = b1[c1];   // bias-as-feature
        w1f[t] = f2bf(v);
    }
    if (t < 16384) {   // B-frags: 4 kt * 8 nt * 64 lane * 8 i
        int i = t & 7, lane = (t >> 3) & 63, nt = (t >> 9) & 7, kt = t >> 12;
        int c = nt * 16 + (lane & 15);
        int h = kt * 32 + (lane >> 4) * 8 + i;
        w2f[t] = f2bf(W2[h * H_DIM + c]);
        wgf[t] = f2bf(Wg[h * OUT_DIM + c]);
    }
    if (gb == E_G / 256 + 255 && threadIdx.x <= 8) {   // batch bounds
        int q = threadIdx.x;
        int a = 0, c = N_PTS;
        while (a < c) { int m = (a + c) >> 1; if (batch[m] < q) a = m + 1; else c = m; }
        bounds[q] = a;
    }
}

// --- fused radius-search + msg + MFMA MLP + max-agg + final GEMV (wave=point)
__global__ __launch_bounds__(256)
__attribute__((amdgpu_waves_per_eu(2, 4)))
void mlp_kernel(
    const unsigned short* __restrict__ xbf, const float* __restrict__ pos,
    const float* __restrict__ normal, const float* __restrict__ edge_attr,
    const u64* __restrict__ htab,
    const int* __restrict__ batch, const int* __restrict__ bounds,
    const unsigned short* __restrict__ w1f, const unsigned short* __restrict__ w2f,
    const unsigned short* __restrict__ wgf,
    const float* __restrict__ b2, const float* __restrict__ bg,
    float* __restrict__ out) {
    __shared__ __align__(16) unsigned char smem[4][4096];
    __shared__ __align__(16) unsigned short aggbf[4 * ARS];
    int tid = threadIdx.x;
    int l = tid & 63, w = tid >> 6;
    int p = blockIdx.x * 4 + w;
    int lo16 = l & 15, hi4 = l >> 4;
    unsigned char* wbase = smem[w];
    int*   nbrlist = (int*)wbase;
    int*   pkrow   = (int*)(wbase + 256);
    float* d2s     = (float*)(wbase + 1280);
    int*   js      = (int*)(wbase + 2304);
    unsigned short* cb = (unsigned short*)(wbase + 1280);

    // ---- phase A: radius ball query (ballot-compacted, coalesced) ----------
    float pxi = pos[p * 3], pyi = pos[p * 3 + 1], pzi = pos[p * 3 + 2];
    float p2i = pxi * pxi + pyi * pyi + pzi * pzi;
    int cnt;
    {
        int b = batch[p];
        int lo = bounds[b], hi = bounds[b + 1];
        int cnt0 = 0;
        for (int j0 = lo; j0 < hi; j0 += 64) {
            int j = j0 + l;
            bool valid = false; float d2 = 0.0f;
            if (j < hi) {
                float xj = pos[j * 3], yj = pos[j * 3 + 1], zj = pos[j * 3 + 2];
                float p2j = xj * xj + yj * yj + zj * zj;
                float dt  = pxi * xj + pyi * yj + pzi * zj;
                d2 = p2i + p2j - 2.0f * dt;   // ref formula; self -> exactly 0
                valid = d2 <= 4.0f;
            }
            unsigned long long mask = __ballot(valid);
            int pp = cnt0 + __popcll(mask & ((1ull << l) - 1ull));
            if (valid && pp < CAND) { d2s[pp] = d2; js[pp] = j; }
            cnt0 += __popcll(mask);
        }
        if (cnt0 > CAND) cnt0 = CAND;
        if (cnt0 <= K_NBR) {
            nbrlist[l] = (l < cnt0) ? js[l] : -1;
        } else {
            // rare: exact top-K by (d2 asc, index asc) == jax top_k tie-break
            for (int idx = l; idx < cnt0; idx += 64) {
                float d2 = d2s[idx]; int jj = js[idx];
                int rank = 0;
                for (int u = 0; u < cnt0; ++u)
                    rank += (d2s[u] < d2) || (d2s[u] == d2 && js[u] < jj);
                if (rank < K_NBR) nbrlist[rank] = jj;
            }
            cnt0 = K_NBR;
        }
        cnt = cnt0;
    }

    // ---- phase B: ppf + edge_attr for own slot -----------------------------
    int jme = nbrlist[l];
    int jc = max(jme, 0);
    float nxi = normal[p * 3], nyi = normal[p * 3 + 1], nzi = normal[p * 3 + 2];
    float pxj = pos[jc * 3], pyj = pos[jc * 3 + 1], pzj = pos[jc * 3 + 2];
    float nxj = normal[jc * 3], nyj = normal[jc * 3 + 1], nzj = normal[jc * 3 + 2];
    float vx = pxj - pxi, vy = pyj - pyi, vz = pzj - pzi;
    float sq = vx * vx + vy * vy + vz * vz;
    float dd = sq > 0.0f ? sqrtf(sq) : 0.0f;
    float a1 = angle3(nxi, nyi, nzi, vx, vy, vz);
    float a2 = angle3(nxj, nyj, nzj, vx, vy, vz);
    float a3 = angle3(nxi, nyi, nzi, nxj, nyj, nzj);
    unsigned key = (unsigned)(jc * N_PTS + p);
    unsigned hh = hash_fn(key);
    unsigned eidx = E_G;   // sentinel row
    for (;;) {
        u64 ent = htab[hh];
        if (ent == EMPTY64) break;
        if ((unsigned)(ent >> 32) == key) { eidx = (unsigned)ent; break; }
        hh = (hh + 1u) & HASH_MASK;
    }
    float4 er = *(const float4*)(edge_attr + (size_t)eidx * D_E);
    int4 pk;
    pk.x = (int)pack2bf(dd, a1);   pk.y = (int)pack2bf(a2, a3);
    pk.z = (int)pack2bf(er.x, er.y); pk.w = (int)pack2bf(er.z, er.w);
    ((int4*)pkrow)[l] = pk;

    // ---- layer 1: D1[c1][slot] = W1^T @ msg^T; LDS-chunk reshuffle to haf --
    bf16x8 haf[4][4];   // [ms][kt]
    #pragma unroll
    for (int pass = 0; pass < 2; ++pass) {
        bf16x8 xf[2][2];    // [nsl][kt]
        bf16x8 ktf[2];
        #pragma unroll
        for (int nsl = 0; nsl < 2; ++nsl) {
            int slot = (pass * 2 + nsl) * 16 + lo16;
            int j = nbrlist[slot];
            const unsigned short* xb = xbf + (size_t)max(j, 0) * F_IN;
            #pragma unroll
            for (int kt = 0; kt < 2; ++kt)
                xf[nsl][kt] = *(const bf16x8*)(xb + kt * 32 + hi4 * 8);
            // kt=2 B-frag: f64..71 = ppf+eattr (hi4==0); f72 bias=1 (hi4==1)
            int4 q = ((const int4*)pkrow)[slot];
            union { bf16x8 v; u32 d[4]; } u;
            u.d[0] = hi4 == 0 ? (u32)q.x : (hi4 == 1 ? 0x3F80u : 0u);
            u.d[1] = hi4 == 0 ? (u32)q.y : 0u;
            u.d[2] = hi4 == 0 ? (u32)q.z : 0u;
            u.d[3] = hi4 == 0 ? (u32)q.w : 0u;
            ktf[nsl] = u.v;
        }
        #pragma unroll
        for (int mtp = 0; mtp < 4; ++mtp) {
            #pragma unroll
            for (int sub = 0; sub < 2; ++sub) {
                int mt = mtp * 2 + sub;
                bf16x8 af0 = *(const bf16x8*)(w1f + ((0 * 8 + mt) * 64 + l) * 8);
                bf16x8 af1 = *(const bf16x8*)(w1f + ((1 * 8 + mt) * 64 + l) * 8);
                bf16x8 af2 = *(const bf16x8*)(w1f + ((2 * 8 + mt) * 64 + l) * 8);
                #pragma unroll
                for (int nsl = 0; nsl < 2; ++nsl) {
                    f32x4 acc = (f32x4)0.0f;
                    acc = __builtin_amdgcn_mfma_f32_16x16x32_bf16(af0, xf[nsl][0], acc, 0, 0, 0);
                    acc = __builtin_amdgcn_mfma_f32_16x16x32_bf16(af1, xf[nsl][1], acc, 0, 0, 0);
                    acc = __builtin_amdgcn_mfma_f32_16x16x32_bf16(af2, ktf[nsl], acc, 0, 0, 0);
                    uint2 o;
                    o.x = pack2t(fmaxf(acc[0], 0.0f), fmaxf(acc[1], 0.0f));
                    o.y = pack2t(fmaxf(acc[2], 0.0f), fmaxf(acc[3], 0.0f));
                    *(uint2*)(cb + (nsl * 16 + lo16) * RSC + sub * 16 + hi4 * 4) = o;
                }
            }
            #pragma unroll
            for (int nsl = 0; nsl < 2; ++nsl)
                haf[pass * 2 + nsl][mtp] =
                    *(const bf16x8*)(cb + (nsl * 16 + lo16) * RSC + hi4 * 8);
        }
    }

    // ---- layer 2: D2[slot][c2] = h1 @ W2 (+b2); masked relu-max over slots -
    #pragma unroll
    for (int nt = 0; nt < 8; ++nt) {
        float bb = b2[nt * 16 + lo16];
        f32x4 acc[4];
        #pragma unroll
        for (int ms = 0; ms < 4; ++ms) { f32x4 bv = {bb, bb, bb, bb}; acc[ms] = bv; }
        #pragma unroll
        for (int kt = 0; kt < 4; ++kt) {
            bf16x8 bfr = *(const bf16x8*)(w2f + ((kt * 8 + nt) * 64 + l) * 8);
            #pragma unroll
            for (int ms = 0; ms < 4; ++ms)
                acc[ms] = __builtin_amdgcn_mfma_f32_16x16x32_bf16(haf[ms][kt], bfr, acc[ms], 0, 0, 0);
        }
        // m starts at 0: max over valid of relu == max(0, max over valid)
        float m = 0.0f;
        #pragma unroll
        for (int ms = 0; ms < 4; ++ms)
            #pragma unroll
            for (int r = 0; r < 4; ++r) {
                int slot = ms * 16 + hi4 * 4 + r;
                m = fmaxf(m, slot < cnt ? acc[ms][r] : 0.0f);
            }
        m = fmaxf(m, __shfl_xor(m, 16, 64));
        m = fmaxf(m, __shfl_xor(m, 32, 64));
        if ((nt >> 1) == hi4)
            aggbf[w * ARS + nt * 16 + lo16] =
                (unsigned short)(__float_as_uint(m) >> 16);
    }

    // ---- fused global_nn: out[4 pts][128] = agg @ Wg + bg ------------------
    __syncthreads();
    int arow = lo16 & 3;
    bf16x8 afr2[4];
    #pragma unroll
    for (int kt = 0; kt < 4; ++kt)
        afr2[kt] = *(const bf16x8*)(aggbf + arow * ARS + kt * 32 + hi4 * 8);
    int ntA = w * 2, ntB = w * 2 + 1;
    f32x4 accA = (f32x4)0.0f, accB = (f32x4)0.0f;
    #pragma unroll
    for (int kt = 0; kt < 4; ++kt) {
        bf16x8 bfrA = *(const bf16x8*)(wgf + ((kt * 8 + ntA) * 64 + l) * 8);
        bf16x8 bfrB = *(const bf16x8*)(wgf + ((kt * 8 + ntB) * 64 + l) * 8);
        accA = __builtin_amdgcn_mfma_f32_16x16x32_bf16(afr2[kt], bfrA, accA, 0, 0, 0);
        accB = __builtin_amdgcn_mfma_f32_16x16x32_bf16(afr2[kt], bfrB, accB, 0, 0, 0);
    }
    if (hi4 == 0) {   // C rows 0..3 = points 0..3
        int cA = ntA * 16 + lo16, cB = ntB * 16 + lo16;
        float bgA = bg[cA], bgB = bg[cB];
        size_t obase = (size_t)(blockIdx.x * 4) * OUT_DIM;
        #pragma unroll
        for (int r = 0; r < 4; ++r) {
            out[obase + (size_t)r * OUT_DIM + cA] = accA[r] + bgA;
            out[obase + (size_t)r * OUT_DIM + cB] = accB[r] + bgB;
        }
    }
}

// ---------------------------------------------------------------------------
extern "C" void kernel_launch(void* const* d_in, const int* in_sizes, int n_in,
                              void* d_out, int out_size, void* d_ws, size_t ws_size,
                              hipStream_t stream) {
    const float* x         = (const float*)d_in[0];
    const float* pos       = (const float*)d_in[1];
    const float* normal    = (const float*)d_in[2];
    const int*   batch     = (const int*)d_in[3];
    const float* edge_attr = (const float*)d_in[4];
    const int*   edge_index= (const int*)d_in[5];
    const float* W1        = (const float*)d_in[6];
    const float* b1        = (const float*)d_in[7];
    const float* W2        = (const float*)d_in[8];
    const float* b2        = (const float*)d_in[9];
    const float* Wg        = (const float*)d_in[10];
    const float* bg        = (const float*)d_in[11];
    float* out = (float*)d_out;

    unsigned char* wsb = (unsigned char*)d_ws;
    u64* htab = (u64*)wsb;                                              // 4 MB
    unsigned short* w1f = (unsigned short*)(wsb + (size_t)HASH_SIZE * 8);
    unsigned short* w2f = w1f + 12288;
    unsigned short* wgf = w2f + 16384;
    unsigned short* xbf = wgf + 16384;                                  // 1 MB
    int* bounds = (int*)(xbf + (size_t)N_PTS * F_IN);

    hipMemsetAsync(htab, 0xFF, (size_t)HASH_SIZE * 8, stream);

    setup_kernel<<<E_G / 256 + 256 + 128, 256, 0, stream>>>(
        edge_index, htab, W1, b1, W2, Wg, x, pos, batch, bounds,
        w1f, w2f, wgf, xbf, out);
    mlp_kernel<<<N_PTS / 4, 256, 0, stream>>>(xbf, pos, normal, edge_attr,
                                              htab, batch, bounds,
                                              w1f, w2f, wgf, b2, bg, out);
}